// Round 11
// baseline (839.325 us; speedup 1.0000x reference)
//
#include <hip/hip_runtime.h>
#include <hip/hip_bf16.h>
#include <cstdint>
#include <cstddef>

namespace {

constexpr int HW = 16384;   // 128*128

typedef short vec8s __attribute__((ext_vector_type(8)));
typedef float f32x4 __attribute__((ext_vector_type(4)));

__device__ __forceinline__ float u2f(uint32_t u){ union { uint32_t u; float f; } v; v.u = u; return v.f; }
__device__ __forceinline__ uint32_t f2u(float f){ union { float f; uint32_t u; } v; v.f = f; return v.u; }
__device__ __forceinline__ uint16_t f2bf(float f){
  uint32_t u = f2u(f);
  u += 0x7fffu + ((u >> 16) & 1u);   // round-to-nearest-even
  return (uint16_t)(u >> 16);
}
__device__ __forceinline__ void unpack2(uint32_t w, float& lo, float& hi){
  lo = u2f(w << 16);
  hi = u2f(w & 0xffff0000u);
}

// ---------------------------------------------------------------------------
// Elementwise fp32 -> bf16 (for weight pre-conversion). n multiple of 8.
// ---------------------------------------------------------------------------
__global__ __launch_bounds__(256) void k_w2bf(
    const float* __restrict__ src, uint16_t* __restrict__ dst, int n)
{
  int i = (blockIdx.x * 256 + threadIdx.x) * 8;
  if (i + 8 <= n) {
    float4 a = *(const float4*)(src + i);
    float4 b = *(const float4*)(src + i + 4);
    uint4 pk;
    pk.x = (uint32_t)f2bf(a.x) | ((uint32_t)f2bf(a.y) << 16);
    pk.y = (uint32_t)f2bf(a.z) | ((uint32_t)f2bf(a.w) << 16);
    pk.z = (uint32_t)f2bf(b.x) | ((uint32_t)f2bf(b.y) << 16);
    pk.w = (uint32_t)f2bf(b.z) | ((uint32_t)f2bf(b.w) << 16);
    *(uint4*)(dst + i) = pk;
  }
}

// ---------------------------------------------------------------------------
// Cast NCHW fp32 (256 ch) -> NHWC bf16. Block = one (b, row).
// ---------------------------------------------------------------------------
__global__ __launch_bounds__(256) void k_cast(
    const float* __restrict__ x, uint16_t* __restrict__ xT)
{
  __shared__ float sF[64][129];
  const int t = threadIdx.x;
  const int b = blockIdx.x >> 7;
  const int y = blockIdx.x & 127;
  const size_t rowoff = (size_t)y * 128;
  for (int cc = 0; cc < 4; ++cc) {
    const int cic0 = cc * 64;
    #pragma unroll
    for (int k = 0; k < 8; ++k) {
      int e = t + k * 256;
      int ci = e >> 5;
      int pxq = (e & 31) * 4;
      float4 v = *(const float4*)(x + (size_t)(b * 256 + cic0 + ci) * HW + rowoff + pxq);
      sF[ci][pxq] = v.x; sF[ci][pxq+1] = v.y; sF[ci][pxq+2] = v.z; sF[ci][pxq+3] = v.w;
    }
    __syncthreads();
    {
      int px = t >> 1, h = t & 1;
      __align__(16) uint16_t tmp[32];
      #pragma unroll
      for (int j = 0; j < 32; ++j) tmp[j] = f2bf(sF[h * 32 + j][px]);
      uint16_t* dst = xT + ((size_t)b * HW + rowoff + px) * 256 + cic0 + h * 32;
      *(uint4*)(dst)      = *(uint4*)&tmp[0];
      *(uint4*)(dst + 8)  = *(uint4*)&tmp[8];
      *(uint4*)(dst + 16) = *(uint4*)&tmp[16];
      *(uint4*)(dst + 24) = *(uint4*)&tmp[24];
    }
    __syncthreads();
  }
}

// ---------------------------------------------------------------------------
// 1x1 conv via bf16 MFMA, X-resident + direct-global bf16 W fragments.
// X tile (128px x 256ci bf16) staged ONCE; after that ZERO barriers:
// per kc-step: 4 ds_read_b128 (X frags) + 4x 16B global loads (W frags,
// L2-resident) + 16 MFMA. wbf layout: [co][ci] bf16, row = cc*128 + wc*64 +
// cf*16 + l15 (identical mapping to v2's sW).
// OUT_MODE 0: NHWC bf16 + BN (pre); 2: NCHW fp32 + BN (pw); 3: qkv windows.
// ---------------------------------------------------------------------------
template<int OUT_MODE, int NCO>
__global__ __launch_bounds__(256) void k_gemm_v3(
    const uint16_t* __restrict__ xT, const uint16_t* __restrict__ wbf,
    const float* __restrict__ bnp, int M,
    uint16_t* __restrict__ outb, float* __restrict__ outf)
{
  __shared__ __align__(16) uint16_t sX[128][260];
  const int t = threadIdx.x;
  const int b    = blockIdx.x >> 7;
  const int tile = blockIdx.x & 127;
  const int l = t & 63, w = t >> 6;
  const int l15 = l & 15, koct = l >> 4;
  const int wc = w >> 1, wp = w & 1;

  {
    const int spx = t >> 1, sh = t & 1;
    int gpx;
    if constexpr (OUT_MODE == 3) {
      int win = tile * 2 + (spx >> 6);
      int p = spx & 63;
      gpx = ((win >> 4) * 8 + (p >> 3)) * 128 + (win & 15) * 8 + (p & 7);
    } else {
      gpx = tile * 128 + spx;
    }
    const uint16_t* src = xT + ((size_t)b * HW + gpx) * 256 + sh * 128;
    uint16_t* dst = &sX[spx][sh * 128];
    #pragma unroll
    for (int i = 0; i < 16; ++i)
      *(uint4*)(dst + i * 8) = *(const uint4*)(src + i * 8);
  }
  __syncthreads();   // X resident; no further barriers

  for (int cc = 0; cc < NCO; ++cc) {
    f32x4 acc[4][4];
    #pragma unroll
    for (int cf = 0; cf < 4; ++cf)
      #pragma unroll
      for (int pf = 0; pf < 4; ++pf) acc[cf][pf] = (f32x4){0.f,0.f,0.f,0.f};

    const uint16_t* wbase = wbf + (size_t)(cc * 128 + wc * 64 + l15) * 256 + koct * 8;
    #pragma unroll
    for (int kc = 0; kc < 8; ++kc) {
      vec8s bf[4];
      #pragma unroll
      for (int pf = 0; pf < 4; ++pf)
        bf[pf] = *(const vec8s*)&sX[wp * 64 + pf * 16 + l15][kc * 32 + koct * 8];
      #pragma unroll
      for (int cf = 0; cf < 4; ++cf) {
        vec8s af = *(const vec8s*)(wbase + (size_t)(cf * 16) * 256 + kc * 32);
        #pragma unroll
        for (int pf = 0; pf < 4; ++pf)
          acc[cf][pf] = __builtin_amdgcn_mfma_f32_16x16x32_bf16(af, bf[pf], acc[cf][pf], 0, 0, 0);
      }
    }

    #pragma unroll
    for (int cf = 0; cf < 4; ++cf) {
      const int cbase = cc * 128 + wc * 64 + cf * 16 + koct * 4;
      float scv[4], shv[4];
      #pragma unroll
      for (int r = 0; r < 4; ++r) {
        scv[r] = 1.f; shv[r] = 0.f;
        if constexpr (OUT_MODE == 0 || OUT_MODE == 2) {
          int c = cbase + r;
          float g = bnp[c], be = bnp[M + c], mu = bnp[2 * M + c], va = bnp[3 * M + c];
          scv[r] = g * rsqrtf(va + 1e-5f);
          shv[r] = be - mu * scv[r];
        }
      }
      #pragma unroll
      for (int pf = 0; pf < 4; ++pf) {
        if constexpr (OUT_MODE == 0) {
          int px = tile * 128 + wp * 64 + pf * 16 + l15;
          __align__(8) uint16_t pk[4];
          #pragma unroll
          for (int r = 0; r < 4; ++r)
            pk[r] = f2bf(fmaf(acc[cf][pf][r], scv[r], shv[r]));
          *(uint2*)(outb + ((size_t)b * HW + px) * 256 + cbase) = *(uint2*)pk;
        } else if constexpr (OUT_MODE == 2) {
          int px = tile * 128 + wp * 64 + pf * 16 + l15;
          #pragma unroll
          for (int r = 0; r < 4; ++r)
            outf[(size_t)(b * M + cbase + r) * HW + px] =
                fmaf(acc[cf][pf][r], scv[r], shv[r]);
        } else {
          int win = tile * 2 + wp;
          int p = pf * 16 + l15;
          uint16_t* dstp = outb + ((size_t)(b * 256 + win) * 768 + cbase) * 64 + p;
          #pragma unroll
          for (int r = 0; r < 4; ++r)
            dstp[(size_t)r * 64] = f2bf(acc[cf][pf][r]);
        }
      }
    }
  }
}

// ---------------------------------------------------------------------------
// Dilated 3x3 conv + BN via bf16 MFMA implicit GEMM (unchanged from r3).
// ---------------------------------------------------------------------------
template<int DIL, int CG>
__global__ __launch_bounds__(256) void k_dilconv_mfma(
    const uint16_t* __restrict__ preT, const float* __restrict__ wt,
    const float* __restrict__ bnp, float* __restrict__ out,
    int cb, int cb_al)
{
  constexpr int R = 8 + 2 * DIL;
  constexpr int C = 64 + 2 * DIL;
  constexpr int NPOS = R * C;
  constexpr int NIT = (NPOS + 255) / 256;
  __shared__ __align__(16) uint16_t sX[NPOS * 16];
  __shared__ __align__(16) uint16_t sW[10 * 50 * 16];

  const int t = threadIdx.x;
  const int rt    = blockIdx.x >> 1;
  const int ctile = blockIdx.x & 1;
  const int ct2   = blockIdx.y;
  const int b     = blockIdx.z;
  const int y0 = rt * 8, x0 = ctile * 64;
  const int l = t & 63, w = t >> 6;
  const int l15 = l & 15, oct = (l >> 4) & 1, half = l >> 5;
  const int rbase = w * 2;

  f32x4 acc[3][8];
  #pragma unroll
  for (int cf = 0; cf < 3; ++cf)
    #pragma unroll
    for (int q = 0; q < 8; ++q) acc[cf][q] = (f32x4){0.f,0.f,0.f,0.f};

  for (int kc = 0; kc < 6; ++kc) {
    #pragma unroll
    for (int i = 0; i < 3; ++i) {
      int pair = t + i * 256;
      int co = pair >> 4, ci = pair & 15;
      int cog = ct2 * 48 + co;
      int c = cb_al + kc * 16 + ci;
      bool ok = (cog < CG) && (c >= cb) && (c < cb + CG);
      size_t widx = ok ? ((size_t)cog * (size_t)CG + (size_t)(c - cb)) * 9u
                       : (size_t)0;
      const float* wp = wt + widx;
      uint16_t* dst = &sW[co * 16 + ci];
      #pragma unroll
      for (int tap = 0; tap < 9; ++tap)
        dst[tap * 800] = ok ? f2bf(wp[tap]) : (uint16_t)0;
      dst[9 * 800] = 0;
    }
    #pragma unroll
    for (int i = 0; i < NIT; ++i) {
      int p = t + i * 256;
      if (p < NPOS) {
        int row = p / C, col = p % C;
        int gy = y0 + row - DIL, gx = x0 + col - DIL;
        uint4 va = {0,0,0,0}, vb = {0,0,0,0};
        if ((unsigned)gy < 128u && (unsigned)gx < 128u) {
          const uint4* src = (const uint4*)(preT +
              (((size_t)b * HW + gy * 128 + gx) * 256 + cb_al + kc * 16));
          va = src[0]; vb = src[1];
        }
        uint4* dst = (uint4*)&sX[p * 16];
        dst[0] = va; dst[1] = vb;
      }
    }
    __syncthreads();

    #pragma unroll
    for (int s = 0; s < 5; ++s) {
      const int tap0 = 2 * s, tap1 = 2 * s + 1;
      const int dy0 = tap0 / 3, dx0 = tap0 % 3;
      const int dy1 = (tap1 <= 8) ? tap1 / 3 : 2;
      const int dx1 = (tap1 <= 8) ? tap1 % 3 : 2;
      const int dy = half ? dy1 : dy0;
      const int dx = half ? dx1 : dx0;
      const int atap = tap0 + half;
      vec8s a0 = *(const vec8s*)&sW[(atap * 50 + 0  + l15) * 16 + oct * 8];
      vec8s a1 = *(const vec8s*)&sW[(atap * 50 + 16 + l15) * 16 + oct * 8];
      vec8s a2 = *(const vec8s*)&sW[(atap * 50 + 32 + l15) * 16 + oct * 8];
      #pragma unroll
      for (int rs = 0; rs < 2; ++rs) {
        const int rowin = rbase + rs + dy * DIL;
        #pragma unroll
        for (int c4 = 0; c4 < 4; ++c4) {
          const int colin = c4 * 16 + l15 + dx * DIL;
          vec8s bf = *(const vec8s*)&sX[(rowin * C + colin) * 16 + oct * 8];
          acc[0][rs*4+c4] = __builtin_amdgcn_mfma_f32_16x16x32_bf16(a0, bf, acc[0][rs*4+c4], 0, 0, 0);
          acc[1][rs*4+c4] = __builtin_amdgcn_mfma_f32_16x16x32_bf16(a1, bf, acc[1][rs*4+c4], 0, 0, 0);
          acc[2][rs*4+c4] = __builtin_amdgcn_mfma_f32_16x16x32_bf16(a2, bf, acc[2][rs*4+c4], 0, 0, 0);
        }
      }
    }
    __syncthreads();
  }

  const int row4 = (l >> 4);
  #pragma unroll
  for (int cf = 0; cf < 3; ++cf) {
    #pragma unroll
    for (int r = 0; r < 4; ++r) {
      int c_loc = ct2 * 48 + cf * 16 + row4 * 4 + r;
      if (c_loc < CG) {
        int cg = cb + c_loc;
        float g = bnp[c_loc], be = bnp[CG + c_loc];
        float mu = bnp[2 * CG + c_loc], va = bnp[3 * CG + c_loc];
        float scv = g * rsqrtf(va + 1e-5f);
        float shv = be - mu * scv;
        #pragma unroll
        for (int rs = 0; rs < 2; ++rs) {
          int y = y0 + rbase + rs;
          #pragma unroll
          for (int c4 = 0; c4 < 4; ++c4) {
            int x = x0 + c4 * 16 + l15;
            out[(size_t)(b * 256 + cg) * HW + y * 128 + x] =
                fmaf(acc[cf][rs*4+c4][r], scv, shv);
          }
        }
      }
    }
  }
}

// ---------------------------------------------------------------------------
// Windowed attention, wave-autonomous + MFMA (unchanged from r8).
// ---------------------------------------------------------------------------
__global__ __launch_bounds__(256) void k_attn(
    const uint16_t* __restrict__ qkvW, const float* __restrict__ rpb,
    uint16_t* __restrict__ outp)
{
  __shared__ __align__(16) uint16_t sAll[4][9928];
  const int t = threadIdx.x;
  const int l = t & 63, w = t >> 6;
  const int l15 = l & 15, koct = l >> 4;
  const int b = blockIdx.y;
  const int win = blockIdx.x;
  const int wy = win >> 4, wx = win & 15;
  const int wbase = (wy * 8) * 128 + wx * 8;
  const uint16_t* base = qkvW + (size_t)(b * 256 + win) * 49152;
  uint16_t* swKT = &sAll[w][0];
  uint16_t* swQT = &sAll[w][2560];
  uint16_t* swPT = &sAll[w][5120];
  float*    swB  = (float*)&sAll[w][9472];
  float*    swO  = (float*)swPT;

  {
    uint4 z = {0,0,0,0};
    *(uint4*)(swKT + l * 40 + 16) = z;
    *(uint4*)(swKT + l * 40 + 24) = z;
    *(uint4*)(swQT + l * 40 + 16) = z;
    *(uint4*)(swQT + l * 40 + 24) = z;
  }

  for (int it = 0; it < 4; ++it) {
    const int n = w + it * 4;
    #pragma unroll
    for (int m = 0; m < 4; ++m) {
      int e = l + m * 64;
      if (e < 225) swB[e] = rpb[e * 16 + n];
    }
    const uint16_t* qg = base + (size_t)(n * 16) * 64;
    const uint16_t* kg = base + (size_t)(256 + n * 16) * 64;
    const uint16_t* vg = base + (size_t)(512 + n * 16) * 64;
    {
      uint32_t kp[8], qp[8];
      #pragma unroll
      for (int m = 0; m < 8; ++m) {
        uint32_t k0 = kg[(2 * m) * 64 + l], k1 = kg[(2 * m + 1) * 64 + l];
        uint32_t q0 = qg[(2 * m) * 64 + l], q1 = qg[(2 * m + 1) * 64 + l];
        kp[m] = k0 | (k1 << 16);
        qp[m] = q0 | (q1 << 16);
      }
      *(uint4*)(swKT + l * 40)     = *(uint4*)&kp[0];
      *(uint4*)(swKT + l * 40 + 8) = *(uint4*)&kp[4];
      *(uint4*)(swQT + l * 40)     = *(uint4*)&qp[0];
      *(uint4*)(swQT + l * 40 + 8) = *(uint4*)&qp[4];
    }
    asm volatile("s_waitcnt lgkmcnt(0)" ::: "memory");
    __builtin_amdgcn_sched_barrier(0);

    vec8s aK[4], bQ[4];
    #pragma unroll
    for (int tt = 0; tt < 4; ++tt) {
      aK[tt] = *(const vec8s*)(swKT + (tt * 16 + l15) * 40 + koct * 8);
      bQ[tt] = *(const vec8s*)(swQT + (tt * 16 + l15) * 40 + koct * 8);
    }
    f32x4 accS[4][4];
    #pragma unroll
    for (int ti = 0; ti < 4; ++ti)
      #pragma unroll
      for (int tj = 0; tj < 4; ++tj)
        accS[ti][tj] = __builtin_amdgcn_mfma_f32_16x16x32_bf16(
            aK[tj], bQ[ti], (f32x4){0.f, 0.f, 0.f, 0.f}, 0, 0, 0);

    float p[4][16], sinv[4];
    #pragma unroll
    for (int ti = 0; ti < 4; ++ti) {
      const int i = ti * 16 + l15;
      const int irow = i >> 3, icol = i & 7;
      #pragma unroll
      for (int tj = 0; tj < 4; ++tj) {
        #pragma unroll
        for (int r = 0; r < 4; ++r) {
          int j = tj * 16 + koct * 4 + r;
          int rel = (irow - (j >> 3) + 7) * 15 + (icol - (j & 7) + 7);
          p[ti][tj * 4 + r] = fmaf(accS[ti][tj][r], 0.25f, swB[rel]);
        }
      }
      float mx = p[ti][0];
      #pragma unroll
      for (int u = 1; u < 16; ++u) mx = fmaxf(mx, p[ti][u]);
      mx = fmaxf(mx, __shfl_xor(mx, 16));
      mx = fmaxf(mx, __shfl_xor(mx, 32));
      float s = 0.f;
      #pragma unroll
      for (int u = 0; u < 16; ++u) { p[ti][u] = __expf(p[ti][u] - mx); s += p[ti][u]; }
      s += __shfl_xor(s, 16);
      s += __shfl_xor(s, 32);
      sinv[ti] = 1.f / s;
    }

    #pragma unroll
    for (int ti = 0; ti < 4; ++ti) {
      uint16_t* rowp = swPT + (ti * 16 + l15) * 68 + koct * 4;
      #pragma unroll
      for (int tj = 0; tj < 4; ++tj) {
        uint32_t u0 = (uint32_t)f2bf(p[ti][tj * 4 + 0]) | ((uint32_t)f2bf(p[ti][tj * 4 + 1]) << 16);
        uint32_t u1 = (uint32_t)f2bf(p[ti][tj * 4 + 2]) | ((uint32_t)f2bf(p[ti][tj * 4 + 3]) << 16);
        *(uint32_t*)(rowp + tj * 16)     = u0;
        *(uint32_t*)(rowp + tj * 16 + 2) = u1;
      }
    }
    asm volatile("s_waitcnt lgkmcnt(0)" ::: "memory");
    __builtin_amdgcn_sched_barrier(0);

    f32x4 accO[4];
    #pragma unroll
    for (int ii = 0; ii < 4; ++ii) accO[ii] = (f32x4){0.f, 0.f, 0.f, 0.f};
    #pragma unroll
    for (int ks = 0; ks < 2; ++ks) {
      vec8s aV = *(const vec8s*)(vg + l15 * 64 + ks * 32 + koct * 8);
      #pragma unroll
      for (int ii = 0; ii < 4; ++ii) {
        vec8s bP;
        const uint16_t* src = swPT + (ii * 16 + l15) * 68 + ks * 32 + koct * 8;
        *(uint2*)&bP         = *(const uint2*)(src);
        *((uint2*)&bP + 1)   = *(const uint2*)(src + 4);
        accO[ii] = __builtin_amdgcn_mfma_f32_16x16x32_bf16(aV, bP, accO[ii], 0, 0, 0);
      }
    }
    asm volatile("s_waitcnt lgkmcnt(0)" ::: "memory");
    __builtin_amdgcn_sched_barrier(0);

    #pragma unroll
    for (int ii = 0; ii < 4; ++ii) {
      #pragma unroll
      for (int r = 0; r < 4; ++r) {
        int dd = koct * 4 + r;
        swO[dd * 76 + ii * 16 + l15] = accO[ii][r] * sinv[ii];
      }
    }
    asm volatile("s_waitcnt lgkmcnt(0)" ::: "memory");
    __builtin_amdgcn_sched_barrier(0);
    #pragma unroll
    for (int e2 = 0; e2 < 2; ++e2) {
      int e = l + e2 * 64;
      int dd = e >> 3, row = e & 7;
      const float* orow = swO + dd * 76 + row * 8;
      float4 a = *(const float4*)(orow);
      float4 c = *(const float4*)(orow + 4);
      uint4 pk;
      pk.x = (uint32_t)f2bf(a.x) | ((uint32_t)f2bf(a.y) << 16);
      pk.y = (uint32_t)f2bf(a.z) | ((uint32_t)f2bf(a.w) << 16);
      pk.z = (uint32_t)f2bf(c.x) | ((uint32_t)f2bf(c.y) << 16);
      pk.w = (uint32_t)f2bf(c.z) | ((uint32_t)f2bf(c.w) << 16);
      *(uint4*)(outp + (size_t)(b * 256 + n * 16 + dd) * HW + wbase + row * 128) = pk;
    }
    asm volatile("s_waitcnt lgkmcnt(0)" ::: "memory");
    __builtin_amdgcn_sched_barrier(0);
  }
}

// ---------------------------------------------------------------------------
// combined = avgpool_v(attn) + avgpool_h(attn) + local (unchanged from r9).
// ---------------------------------------------------------------------------
__global__ __launch_bounds__(256) void k_pool(
    const uint16_t* __restrict__ attnb, float* __restrict__ loc)
{
  __shared__ __align__(16) float sP[71][136];
  const int t = threadIdx.x;
  const int plane = blockIdx.x >> 1;
  const int h0 = (blockIdx.x & 1) * 64;
  const size_t pbase = (size_t)plane * HW;
  #pragma unroll
  for (int k = 0; k < 5; ++k) {
    int idx = t + k * 256;
    if (idx < 71 * 16) {
      int lr = idx >> 4, m = idx & 15;
      int g = h0 - 3 + lr;
      float f[8] = {0.f,0.f,0.f,0.f,0.f,0.f,0.f,0.f};
      if (g >= 0 && g <= 127) {
        uint4 v4 = *(const uint4*)(attnb + pbase + (size_t)g * 128 + m * 8);
        unpack2(v4.x, f[0], f[1]); unpack2(v4.y, f[2], f[3]);
        unpack2(v4.z, f[4], f[5]); unpack2(v4.w, f[6], f[7]);
      }
      float* dst = &sP[lr][4 + m * 8];
      *(float4*)dst       = (float4){f[0], f[1], f[2], f[3]};
      *(float4*)(dst + 4) = (float4){f[4], f[5], f[6], f[7]};
    }
  }
  #pragma unroll
  for (int k = 0; k < 3; ++k) {
    int idx = t + k * 256;
    if (idx < 71 * 8) {
      int lr = idx >> 3, e = idx & 7;
      int c = (e < 4) ? e : (128 + e);
      sP[lr][c] = 0.f;
    }
  }
  __syncthreads();

  const int q  = t & 31;
  const int r0 = (t >> 5) * 8;
  const int w0 = q * 4;
  float4 av = {0.f, 0.f, 0.f, 0.f};
  #pragma unroll
  for (int o = 0; o < 8; ++o) {
    float4 v = *(const float4*)&sP[r0 + o][4 + w0];
    av.x += v.x; av.y += v.y; av.z += v.z; av.w += v.w;
  }
  #pragma unroll
  for (int rr = 0; rr < 8; ++rr) {
    const int lh = r0 + rr;
    const int h = h0 + lh;
    float4 a = av;
    if (h >= 124) {
      float4 cfix = *(const float4*)&sP[126 - 64 + 3][4 + w0];
      a.x += cfix.x; a.y += cfix.y; a.z += cfix.z; a.w += cfix.w;
    }
    float4 hv0 = *(const float4*)&sP[lh + 3][w0];
    float4 hv1 = *(const float4*)&sP[lh + 3][w0 + 4];
    float4 hv2 = *(const float4*)&sP[lh + 3][w0 + 8];
    float s0 = hv0.y + hv0.z + hv0.w + hv1.x + hv1.y + hv1.z + hv1.w + hv2.x;
    float s1 = s0 - hv0.y + hv2.y;
    float s2 = s1 - hv0.z + hv2.z;
    float s3 = s2 - hv0.w + hv2.w;
    if (q == 31) {
      float cfix = sP[lh + 3][130];
      s0 += cfix; s1 += cfix; s2 += cfix; s3 += cfix;
    }
    const size_t gi = pbase + (size_t)h * 128 + w0;
    float4 lv = *(const float4*)(loc + gi);
    float4 o4;
    o4.x = fmaf(a.x + s0, 0.125f, lv.x);
    o4.y = fmaf(a.y + s1, 0.125f, lv.y);
    o4.z = fmaf(a.z + s2, 0.125f, lv.z);
    o4.w = fmaf(a.w + s3, 0.125f, lv.w);
    *(float4*)(loc + gi) = o4;
    if (rr < 7) {
      float4 vm = *(const float4*)&sP[lh][4 + w0];
      float4 vp = *(const float4*)&sP[lh + 8][4 + w0];
      av.x += vp.x - vm.x; av.y += vp.y - vm.y;
      av.z += vp.z - vm.z; av.w += vp.w - vm.w;
    }
  }
}

// ---------------------------------------------------------------------------
// Depthwise 8x8 conv (unchanged from r10).
// ---------------------------------------------------------------------------
__global__ __launch_bounds__(256) void k_dw(
    const float* __restrict__ comb, const float* __restrict__ wdw,
    float* __restrict__ out)
{
  __shared__ __align__(16) float sZ[71][136];
  __shared__ float sWd[64];
  const int t = threadIdx.x;
  const int plane = blockIdx.x >> 1;
  const int cch = plane & 255;
  const int h0 = (blockIdx.x & 1) * 64;
  const size_t pbase = (size_t)plane * HW;
  if (t < 64) sWd[t] = wdw[cch * 64 + t];
  #pragma unroll
  for (int k = 0; k < 5; ++k) {
    int idx = t + k * 256;
    if (idx < 71 * 16) {
      int lr = idx >> 4, m = idx & 15;
      int g = h0 - 3 + lr;
      float4 a = {0.f,0.f,0.f,0.f}, c = {0.f,0.f,0.f,0.f};
      if (g >= 0 && g <= 128) {
        int gr = (g == 128) ? 126 : g;
        const float* src = comb + pbase + (size_t)gr * 128 + m * 8;
        a = *(const float4*)(src);
        c = *(const float4*)(src + 4);
      }
      float* dst = &sZ[lr][4 + m * 8];
      *(float4*)dst       = a;
      *(float4*)(dst + 4) = c;
    }
  }
  if (t < 71) {
    int lr = t;
    int g = h0 - 3 + lr;
    float rv = 0.f;
    if (g >= 0 && g <= 128) {
      int gr = (g == 128) ? 126 : g;
      rv = comb[pbase + (size_t)gr * 128 + 126];
    }
    *(float4*)&sZ[lr][0] = (float4){0.f, 0.f, 0.f, 0.f};
    sZ[lr][132] = rv;
    sZ[lr][133] = 0.f; sZ[lr][134] = 0.f; sZ[lr][135] = 0.f;
  }
  __syncthreads();

  float wt[8][8];
  #pragma unroll
  for (int i = 0; i < 8; ++i) {
    *(float4*)&wt[i][0] = *(const float4*)&sWd[i * 8];
    *(float4*)&wt[i][4] = *(const float4*)&sWd[i * 8 + 4];
  }

  const int q  = t & 31;
  const int rg = t >> 5;
  const int w0 = q * 4;
  f32x4 acc[8];
  #pragma unroll
  for (int rr = 0; rr < 8; ++rr) acc[rr] = (f32x4){0.f,0.f,0.f,0.f};

  #pragma unroll
  for (int v = 0; v < 15; ++v) {
    const int lr = rg * 8 + v;
    float win[12];
    *(float4*)&win[0] = *(const float4*)&sZ[lr][w0];
    *(float4*)&win[4] = *(const float4*)&sZ[lr][w0 + 4];
    *(float4*)&win[8] = *(const float4*)&sZ[lr][w0 + 8];
    #pragma unroll
    for (int rr = 0; rr < 8; ++rr) {
      const int i = v - rr;
      if (i >= 0 && i < 8) {
        #pragma unroll
        for (int c = 0; c < 4; ++c) {
          float s = acc[rr][c];
          #pragma unroll
          for (int j = 0; j < 8; ++j)
            s = fmaf(wt[i][j], win[c + j + 1], s);
          acc[rr][c] = s;
        }
      }
    }
  }
  #pragma unroll
  for (int rr = 0; rr < 8; ++rr) {
    int h = h0 + rg * 8 + rr;
    float* dst = out + pbase + (size_t)h * 128 + w0;
    *(float4*)dst = (float4){acc[rr][0], acc[rr][1], acc[rr][2], acc[rr][3]};
  }
}

} // namespace

extern "C" void kernel_launch(void* const* d_in, const int* in_sizes, int n_in,
                              void* d_out, int out_size, void* d_ws, size_t ws_size,
                              hipStream_t stream)
{
  const float* x      = (const float*)d_in[0];
  const float* w_pre  = (const float*)d_in[1];
  const float* bn_pre = (const float*)d_in[2];
  const float* w_l1   = (const float*)d_in[3];
  const float* bn_l1  = (const float*)d_in[4];
  const float* w_l2   = (const float*)d_in[5];
  const float* bn_l2  = (const float*)d_in[6];
  const float* w_l3   = (const float*)d_in[7];
  const float* bn_l3  = (const float*)d_in[8];
  const float* w_qkv  = (const float*)d_in[9];
  const float* rpb    = (const float*)d_in[10];
  const float* w_dw   = (const float*)d_in[11];
  const float* w_pw   = (const float*)d_in[12];
  const float* bn_pj  = (const float*)d_in[13];
  float* out = (float*)d_out;

  char* base = (char*)d_ws;
  uint16_t* xT    = (uint16_t*)base;                          // 64 MiB NHWC bf16 x; later dwT
  uint16_t* preT  = (uint16_t*)(base + (size_t)67108864);     // 64 MiB NHWC bf16 pre; later attn out; tail holds wpw_bf late
  float*    bufB  = (float*)(base + (size_t)134217728);       // 128 MiB fp32 local/combined
  uint16_t* bufQ  = (uint16_t*)(base + (size_t)268435456);    // 192 MiB bf16 qkv windows; later dw out
  uint16_t* attnO = preT;
  float*    bufDw = (float*)bufQ;
  uint16_t* dwT   = xT;
  // bf16 weights: wpre/wqkv live in d_out (free until step 8);
  // wpw lives in preT region (free after step 5).
  uint16_t* wpre_bf = (uint16_t*)out;
  uint16_t* wqkv_bf = wpre_bf + 65536;
  uint16_t* wpw_bf  = preT;

  dim3 blk(256);
  // W pre-conversion (wpre, wqkv -> d_out scratch)
  k_w2bf<<<dim3(32),  blk, 0, stream>>>(w_pre, wpre_bf, 65536);
  k_w2bf<<<dim3(96),  blk, 0, stream>>>(w_qkv, wqkv_bf, 196608);
  // 0. cast x -> NHWC bf16
  k_cast<<<dim3(1024), blk, 0, stream>>>(x, xT);
  // 1. pre 1x1 conv + bn -> NHWC bf16 (MFMA v3, barrier-free K-loop)
  k_gemm_v3<0, 2><<<dim3(1024), blk, 0, stream>>>(xT, wpre_bf, bn_pre, 256, preT, nullptr);
  // 2. dilated 3x3 convs + bn (MFMA) -> bufB fp32 NCHW
  k_dilconv_mfma<1, 86><<<dim3(32, 2, 8), blk, 0, stream>>>(preT, w_l1, bn_l1, bufB, 0, 0);
  k_dilconv_mfma<2, 86><<<dim3(32, 2, 8), blk, 0, stream>>>(preT, w_l2, bn_l2, bufB, 86, 80);
  k_dilconv_mfma<3, 84><<<dim3(32, 2, 8), blk, 0, stream>>>(preT, w_l3, bn_l3, bufB, 172, 160);
  // 3. qkv 1x1 conv -> bufQ window-layout bf16 (MFMA v3)
  k_gemm_v3<3, 6><<<dim3(1024), blk, 0, stream>>>(xT, wqkv_bf, nullptr, 768, bufQ, nullptr);
  // 4. windowed attention (MFMA) -> attnO bf16 NCHW (overwrites preT; safe)
  k_attn<<<dim3(256, 8), blk, 0, stream>>>(bufQ, rpb, attnO);
  // 5. pools + residual combine (in-place on bufB)
  k_pool<<<dim3(4096), blk, 0, stream>>>(attnO, bufB);
  // 5b. wpw -> bf16 into preT region (attnO dead after pool)
  k_w2bf<<<dim3(32), blk, 0, stream>>>(w_pw, wpw_bf, 65536);
  // 6. depthwise 8x8 -> bufDw fp32 NCHW (overwrites bufQ; safe)
  k_dw<<<dim3(4096), blk, 0, stream>>>(bufB, w_dw, bufDw);
  // 7. cast dw-out -> NHWC bf16 (overwrites xT; safe)
  k_cast<<<dim3(1024), blk, 0, stream>>>(bufDw, dwT);
  // 8. pw 1x1 conv + bn -> out fp32 NCHW (MFMA v3; wpw_bf in preT region)
  k_gemm_v3<2, 2><<<dim3(1024), blk, 0, stream>>>(dwT, wpw_bf, bn_pj, 256, nullptr, out);

  (void)in_sizes; (void)n_in; (void)out_size; (void)ws_size;
}

// Round 12
// 729.715 us; speedup vs baseline: 1.1502x; 1.1502x over previous
//
#include <hip/hip_runtime.h>
#include <hip/hip_bf16.h>
#include <cstdint>
#include <cstddef>

namespace {

constexpr int HW = 16384;   // 128*128

typedef short vec8s __attribute__((ext_vector_type(8)));
typedef float f32x4 __attribute__((ext_vector_type(4)));

__device__ __forceinline__ float u2f(uint32_t u){ union { uint32_t u; float f; } v; v.u = u; return v.f; }
__device__ __forceinline__ uint32_t f2u(float f){ union { float f; uint32_t u; } v; v.f = f; return v.u; }
__device__ __forceinline__ uint16_t f2bf(float f){
  uint32_t u = f2u(f);
  u += 0x7fffu + ((u >> 16) & 1u);   // round-to-nearest-even
  return (uint16_t)(u >> 16);
}
__device__ __forceinline__ void unpack2(uint32_t w, float& lo, float& hi){
  lo = u2f(w << 16);
  hi = u2f(w & 0xffff0000u);
}

// ---------------------------------------------------------------------------
// Elementwise fp32 -> bf16 (weight pre-conversion). n multiple of 8.
// ---------------------------------------------------------------------------
__global__ __launch_bounds__(256) void k_w2bf(
    const float* __restrict__ src, uint16_t* __restrict__ dst, int n)
{
  int i = (blockIdx.x * 256 + threadIdx.x) * 8;
  if (i + 8 <= n) {
    float4 a = *(const float4*)(src + i);
    float4 b = *(const float4*)(src + i + 4);
    uint4 pk;
    pk.x = (uint32_t)f2bf(a.x) | ((uint32_t)f2bf(a.y) << 16);
    pk.y = (uint32_t)f2bf(a.z) | ((uint32_t)f2bf(a.w) << 16);
    pk.z = (uint32_t)f2bf(b.x) | ((uint32_t)f2bf(b.y) << 16);
    pk.w = (uint32_t)f2bf(b.z) | ((uint32_t)f2bf(b.w) << 16);
    *(uint4*)(dst + i) = pk;
  }
}

// ---------------------------------------------------------------------------
// Cast NCHW fp32 (256 ch) -> NHWC bf16. Block = one (b, row).
// ---------------------------------------------------------------------------
__global__ __launch_bounds__(256) void k_cast(
    const float* __restrict__ x, uint16_t* __restrict__ xT)
{
  __shared__ float sF[64][129];
  const int t = threadIdx.x;
  const int b = blockIdx.x >> 7;
  const int y = blockIdx.x & 127;
  const size_t rowoff = (size_t)y * 128;
  for (int cc = 0; cc < 4; ++cc) {
    const int cic0 = cc * 64;
    #pragma unroll
    for (int k = 0; k < 8; ++k) {
      int e = t + k * 256;
      int ci = e >> 5;
      int pxq = (e & 31) * 4;
      float4 v = *(const float4*)(x + (size_t)(b * 256 + cic0 + ci) * HW + rowoff + pxq);
      sF[ci][pxq] = v.x; sF[ci][pxq+1] = v.y; sF[ci][pxq+2] = v.z; sF[ci][pxq+3] = v.w;
    }
    __syncthreads();
    {
      int px = t >> 1, h = t & 1;
      __align__(16) uint16_t tmp[32];
      #pragma unroll
      for (int j = 0; j < 32; ++j) tmp[j] = f2bf(sF[h * 32 + j][px]);
      uint16_t* dst = xT + ((size_t)b * HW + rowoff + px) * 256 + cic0 + h * 32;
      *(uint4*)(dst)      = *(uint4*)&tmp[0];
      *(uint4*)(dst + 8)  = *(uint4*)&tmp[8];
      *(uint4*)(dst + 16) = *(uint4*)&tmp[16];
      *(uint4*)(dst + 24) = *(uint4*)&tmp[24];
    }
    __syncthreads();
  }
}

// ---------------------------------------------------------------------------
// 1x1 conv via bf16 MFMA, X-resident co-loop (r10 structure) with
// PRE-CONVERTED bf16 W: stage = pure 32B copy (reg-prefetched), no f2bf.
// OUT_MODE 0: NHWC bf16 + BN (pre); 2: NCHW fp32 + BN (pw); 3: qkv windows.
// ---------------------------------------------------------------------------
template<int OUT_MODE, int NCO>
__global__ __launch_bounds__(256) void k_gemm_v2(
    const uint16_t* __restrict__ xT, const uint16_t* __restrict__ wbf,
    const float* __restrict__ bnp, int M,
    uint16_t* __restrict__ outb, float* __restrict__ outf)
{
  __shared__ __align__(16) uint16_t sX[128][260];
  __shared__ __align__(16) uint16_t sW[128][36];
  const int t = threadIdx.x;
  const int b    = blockIdx.x >> 7;
  const int tile = blockIdx.x & 127;
  const int l = t & 63, w = t >> 6;
  const int l15 = l & 15, koct = l >> 4;
  const int wc = w >> 1, wp = w & 1;     // wave co-half / px-half

  // ---- stage X tile once ----
  {
    const int spx = t >> 1, sh = t & 1;
    int gpx;
    if constexpr (OUT_MODE == 3) {
      int win = tile * 2 + (spx >> 6);
      int p = spx & 63;
      gpx = ((win >> 4) * 8 + (p >> 3)) * 128 + (win & 15) * 8 + (p & 7);
    } else {
      gpx = tile * 128 + spx;
    }
    const uint16_t* src = xT + ((size_t)b * HW + gpx) * 256 + sh * 128;
    uint16_t* dst = &sX[spx][sh * 128];
    #pragma unroll
    for (int i = 0; i < 16; ++i)
      *(uint4*)(dst + i * 8) = *(const uint4*)(src + i * 8);
  }

  // ---- W prefetch (bf16): thread t -> co row t>>1, 16-ci half t&1 ----
  const int swc = t >> 1, swh = t & 1;
  uint4 wr0, wr1;
  {
    const uint16_t* p = wbf + (size_t)swc * 256 + swh * 16;   // cc=0, kc=0
    wr0 = *(const uint4*)(p);
    wr1 = *(const uint4*)(p + 8);
  }
  __syncthreads();   // X resident

  for (int cc = 0; cc < NCO; ++cc) {
    f32x4 acc[4][4];
    #pragma unroll
    for (int cf = 0; cf < 4; ++cf)
      #pragma unroll
      for (int pf = 0; pf < 4; ++pf) acc[cf][pf] = (f32x4){0.f,0.f,0.f,0.f};

    for (int kc = 0; kc < 8; ++kc) {
      if (cc | kc) __syncthreads();          // prior readers of sW done
      {
        uint16_t* dst = &sW[swc][swh * 16];
        *(uint4*)(dst)     = wr0;
        *(uint4*)(dst + 8) = wr1;
      }
      {
        int nkc = kc + 1, ncc = cc;
        if (nkc == 8) { nkc = 0; ncc = cc + 1; }
        if (ncc < NCO) {   // issue next W loads early (hide under MFMA)
          const uint16_t* p = wbf + (size_t)(ncc * 128 + swc) * 256 + nkc * 32 + swh * 16;
          wr0 = *(const uint4*)(p);
          wr1 = *(const uint4*)(p + 8);
        }
      }
      __syncthreads();                        // sW chunk ready
      vec8s bf[4];
      #pragma unroll
      for (int pf = 0; pf < 4; ++pf)
        bf[pf] = *(const vec8s*)&sX[wp * 64 + pf * 16 + l15][kc * 32 + koct * 8];
      #pragma unroll
      for (int cf = 0; cf < 4; ++cf) {
        vec8s af = *(const vec8s*)&sW[wc * 64 + cf * 16 + l15][koct * 8];
        #pragma unroll
        for (int pf = 0; pf < 4; ++pf)
          acc[cf][pf] = __builtin_amdgcn_mfma_f32_16x16x32_bf16(af, bf[pf], acc[cf][pf], 0, 0, 0);
      }
    }

    // ---- epilogue for this co chunk ----
    #pragma unroll
    for (int cf = 0; cf < 4; ++cf) {
      const int cbase = cc * 128 + wc * 64 + cf * 16 + koct * 4;
      float scv[4], shv[4];
      #pragma unroll
      for (int r = 0; r < 4; ++r) {
        scv[r] = 1.f; shv[r] = 0.f;
        if constexpr (OUT_MODE == 0 || OUT_MODE == 2) {
          int c = cbase + r;
          float g = bnp[c], be = bnp[M + c], mu = bnp[2 * M + c], va = bnp[3 * M + c];
          scv[r] = g * rsqrtf(va + 1e-5f);
          shv[r] = be - mu * scv[r];
        }
      }
      #pragma unroll
      for (int pf = 0; pf < 4; ++pf) {
        if constexpr (OUT_MODE == 0) {
          int px = tile * 128 + wp * 64 + pf * 16 + l15;
          __align__(8) uint16_t pk[4];
          #pragma unroll
          for (int r = 0; r < 4; ++r)
            pk[r] = f2bf(fmaf(acc[cf][pf][r], scv[r], shv[r]));
          *(uint2*)(outb + ((size_t)b * HW + px) * 256 + cbase) = *(uint2*)pk;
        } else if constexpr (OUT_MODE == 2) {
          int px = tile * 128 + wp * 64 + pf * 16 + l15;
          #pragma unroll
          for (int r = 0; r < 4; ++r)
            outf[(size_t)(b * M + cbase + r) * HW + px] =
                fmaf(acc[cf][pf][r], scv[r], shv[r]);
        } else {
          int win = tile * 2 + wp;
          int p = pf * 16 + l15;
          uint16_t* dstp = outb + ((size_t)(b * 256 + win) * 768 + cbase) * 64 + p;
          #pragma unroll
          for (int r = 0; r < 4; ++r)
            dstp[(size_t)r * 64] = f2bf(acc[cf][pf][r]);
        }
      }
    }
  }
}

// ---------------------------------------------------------------------------
// Dilated 3x3 conv + BN via bf16 MFMA implicit GEMM (unchanged from r3).
// ---------------------------------------------------------------------------
template<int DIL, int CG>
__global__ __launch_bounds__(256) void k_dilconv_mfma(
    const uint16_t* __restrict__ preT, const float* __restrict__ wt,
    const float* __restrict__ bnp, float* __restrict__ out,
    int cb, int cb_al)
{
  constexpr int R = 8 + 2 * DIL;
  constexpr int C = 64 + 2 * DIL;
  constexpr int NPOS = R * C;
  constexpr int NIT = (NPOS + 255) / 256;
  __shared__ __align__(16) uint16_t sX[NPOS * 16];
  __shared__ __align__(16) uint16_t sW[10 * 50 * 16];

  const int t = threadIdx.x;
  const int rt    = blockIdx.x >> 1;
  const int ctile = blockIdx.x & 1;
  const int ct2   = blockIdx.y;
  const int b     = blockIdx.z;
  const int y0 = rt * 8, x0 = ctile * 64;
  const int l = t & 63, w = t >> 6;
  const int l15 = l & 15, oct = (l >> 4) & 1, half = l >> 5;
  const int rbase = w * 2;

  f32x4 acc[3][8];
  #pragma unroll
  for (int cf = 0; cf < 3; ++cf)
    #pragma unroll
    for (int q = 0; q < 8; ++q) acc[cf][q] = (f32x4){0.f,0.f,0.f,0.f};

  for (int kc = 0; kc < 6; ++kc) {
    #pragma unroll
    for (int i = 0; i < 3; ++i) {
      int pair = t + i * 256;
      int co = pair >> 4, ci = pair & 15;
      int cog = ct2 * 48 + co;
      int c = cb_al + kc * 16 + ci;
      bool ok = (cog < CG) && (c >= cb) && (c < cb + CG);
      size_t widx = ok ? ((size_t)cog * (size_t)CG + (size_t)(c - cb)) * 9u
                       : (size_t)0;
      const float* wp = wt + widx;
      uint16_t* dst = &sW[co * 16 + ci];
      #pragma unroll
      for (int tap = 0; tap < 9; ++tap)
        dst[tap * 800] = ok ? f2bf(wp[tap]) : (uint16_t)0;
      dst[9 * 800] = 0;
    }
    #pragma unroll
    for (int i = 0; i < NIT; ++i) {
      int p = t + i * 256;
      if (p < NPOS) {
        int row = p / C, col = p % C;
        int gy = y0 + row - DIL, gx = x0 + col - DIL;
        uint4 va = {0,0,0,0}, vb = {0,0,0,0};
        if ((unsigned)gy < 128u && (unsigned)gx < 128u) {
          const uint4* src = (const uint4*)(preT +
              (((size_t)b * HW + gy * 128 + gx) * 256 + cb_al + kc * 16));
          va = src[0]; vb = src[1];
        }
        uint4* dst = (uint4*)&sX[p * 16];
        dst[0] = va; dst[1] = vb;
      }
    }
    __syncthreads();

    #pragma unroll
    for (int s = 0; s < 5; ++s) {
      const int tap0 = 2 * s, tap1 = 2 * s + 1;
      const int dy0 = tap0 / 3, dx0 = tap0 % 3;
      const int dy1 = (tap1 <= 8) ? tap1 / 3 : 2;
      const int dx1 = (tap1 <= 8) ? tap1 % 3 : 2;
      const int dy = half ? dy1 : dy0;
      const int dx = half ? dx1 : dx0;
      const int atap = tap0 + half;
      vec8s a0 = *(const vec8s*)&sW[(atap * 50 + 0  + l15) * 16 + oct * 8];
      vec8s a1 = *(const vec8s*)&sW[(atap * 50 + 16 + l15) * 16 + oct * 8];
      vec8s a2 = *(const vec8s*)&sW[(atap * 50 + 32 + l15) * 16 + oct * 8];
      #pragma unroll
      for (int rs = 0; rs < 2; ++rs) {
        const int rowin = rbase + rs + dy * DIL;
        #pragma unroll
        for (int c4 = 0; c4 < 4; ++c4) {
          const int colin = c4 * 16 + l15 + dx * DIL;
          vec8s bf = *(const vec8s*)&sX[(rowin * C + colin) * 16 + oct * 8];
          acc[0][rs*4+c4] = __builtin_amdgcn_mfma_f32_16x16x32_bf16(a0, bf, acc[0][rs*4+c4], 0, 0, 0);
          acc[1][rs*4+c4] = __builtin_amdgcn_mfma_f32_16x16x32_bf16(a1, bf, acc[1][rs*4+c4], 0, 0, 0);
          acc[2][rs*4+c4] = __builtin_amdgcn_mfma_f32_16x16x32_bf16(a2, bf, acc[2][rs*4+c4], 0, 0, 0);
        }
      }
    }
    __syncthreads();
  }

  const int row4 = (l >> 4);
  #pragma unroll
  for (int cf = 0; cf < 3; ++cf) {
    #pragma unroll
    for (int r = 0; r < 4; ++r) {
      int c_loc = ct2 * 48 + cf * 16 + row4 * 4 + r;
      if (c_loc < CG) {
        int cg = cb + c_loc;
        float g = bnp[c_loc], be = bnp[CG + c_loc];
        float mu = bnp[2 * CG + c_loc], va = bnp[3 * CG + c_loc];
        float scv = g * rsqrtf(va + 1e-5f);
        float shv = be - mu * scv;
        #pragma unroll
        for (int rs = 0; rs < 2; ++rs) {
          int y = y0 + rbase + rs;
          #pragma unroll
          for (int c4 = 0; c4 < 4; ++c4) {
            int x = x0 + c4 * 16 + l15;
            out[(size_t)(b * 256 + cg) * HW + y * 128 + x] =
                fmaf(acc[cf][rs*4+c4][r], scv, shv);
          }
        }
      }
    }
  }
}

// ---------------------------------------------------------------------------
// Windowed attention, wave-autonomous + MFMA (unchanged from r8).
// ---------------------------------------------------------------------------
__global__ __launch_bounds__(256) void k_attn(
    const uint16_t* __restrict__ qkvW, const float* __restrict__ rpb,
    uint16_t* __restrict__ outp)
{
  __shared__ __align__(16) uint16_t sAll[4][9928];
  const int t = threadIdx.x;
  const int l = t & 63, w = t >> 6;
  const int l15 = l & 15, koct = l >> 4;
  const int b = blockIdx.y;
  const int win = blockIdx.x;
  const int wy = win >> 4, wx = win & 15;
  const int wbase = (wy * 8) * 128 + wx * 8;
  const uint16_t* base = qkvW + (size_t)(b * 256 + win) * 49152;
  uint16_t* swKT = &sAll[w][0];
  uint16_t* swQT = &sAll[w][2560];
  uint16_t* swPT = &sAll[w][5120];
  float*    swB  = (float*)&sAll[w][9472];
  float*    swO  = (float*)swPT;

  {
    uint4 z = {0,0,0,0};
    *(uint4*)(swKT + l * 40 + 16) = z;
    *(uint4*)(swKT + l * 40 + 24) = z;
    *(uint4*)(swQT + l * 40 + 16) = z;
    *(uint4*)(swQT + l * 40 + 24) = z;
  }

  for (int it = 0; it < 4; ++it) {
    const int n = w + it * 4;
    #pragma unroll
    for (int m = 0; m < 4; ++m) {
      int e = l + m * 64;
      if (e < 225) swB[e] = rpb[e * 16 + n];
    }
    const uint16_t* qg = base + (size_t)(n * 16) * 64;
    const uint16_t* kg = base + (size_t)(256 + n * 16) * 64;
    const uint16_t* vg = base + (size_t)(512 + n * 16) * 64;
    {
      uint32_t kp[8], qp[8];
      #pragma unroll
      for (int m = 0; m < 8; ++m) {
        uint32_t k0 = kg[(2 * m) * 64 + l], k1 = kg[(2 * m + 1) * 64 + l];
        uint32_t q0 = qg[(2 * m) * 64 + l], q1 = qg[(2 * m + 1) * 64 + l];
        kp[m] = k0 | (k1 << 16);
        qp[m] = q0 | (q1 << 16);
      }
      *(uint4*)(swKT + l * 40)     = *(uint4*)&kp[0];
      *(uint4*)(swKT + l * 40 + 8) = *(uint4*)&kp[4];
      *(uint4*)(swQT + l * 40)     = *(uint4*)&qp[0];
      *(uint4*)(swQT + l * 40 + 8) = *(uint4*)&qp[4];
    }
    asm volatile("s_waitcnt lgkmcnt(0)" ::: "memory");
    __builtin_amdgcn_sched_barrier(0);

    vec8s aK[4], bQ[4];
    #pragma unroll
    for (int tt = 0; tt < 4; ++tt) {
      aK[tt] = *(const vec8s*)(swKT + (tt * 16 + l15) * 40 + koct * 8);
      bQ[tt] = *(const vec8s*)(swQT + (tt * 16 + l15) * 40 + koct * 8);
    }
    f32x4 accS[4][4];
    #pragma unroll
    for (int ti = 0; ti < 4; ++ti)
      #pragma unroll
      for (int tj = 0; tj < 4; ++tj)
        accS[ti][tj] = __builtin_amdgcn_mfma_f32_16x16x32_bf16(
            aK[tj], bQ[ti], (f32x4){0.f, 0.f, 0.f, 0.f}, 0, 0, 0);

    float p[4][16], sinv[4];
    #pragma unroll
    for (int ti = 0; ti < 4; ++ti) {
      const int i = ti * 16 + l15;
      const int irow = i >> 3, icol = i & 7;
      #pragma unroll
      for (int tj = 0; tj < 4; ++tj) {
        #pragma unroll
        for (int r = 0; r < 4; ++r) {
          int j = tj * 16 + koct * 4 + r;
          int rel = (irow - (j >> 3) + 7) * 15 + (icol - (j & 7) + 7);
          p[ti][tj * 4 + r] = fmaf(accS[ti][tj][r], 0.25f, swB[rel]);
        }
      }
      float mx = p[ti][0];
      #pragma unroll
      for (int u = 1; u < 16; ++u) mx = fmaxf(mx, p[ti][u]);
      mx = fmaxf(mx, __shfl_xor(mx, 16));
      mx = fmaxf(mx, __shfl_xor(mx, 32));
      float s = 0.f;
      #pragma unroll
      for (int u = 0; u < 16; ++u) { p[ti][u] = __expf(p[ti][u] - mx); s += p[ti][u]; }
      s += __shfl_xor(s, 16);
      s += __shfl_xor(s, 32);
      sinv[ti] = 1.f / s;
    }

    #pragma unroll
    for (int ti = 0; ti < 4; ++ti) {
      uint16_t* rowp = swPT + (ti * 16 + l15) * 68 + koct * 4;
      #pragma unroll
      for (int tj = 0; tj < 4; ++tj) {
        uint32_t u0 = (uint32_t)f2bf(p[ti][tj * 4 + 0]) | ((uint32_t)f2bf(p[ti][tj * 4 + 1]) << 16);
        uint32_t u1 = (uint32_t)f2bf(p[ti][tj * 4 + 2]) | ((uint32_t)f2bf(p[ti][tj * 4 + 3]) << 16);
        *(uint32_t*)(rowp + tj * 16)     = u0;
        *(uint32_t*)(rowp + tj * 16 + 2) = u1;
      }
    }
    asm volatile("s_waitcnt lgkmcnt(0)" ::: "memory");
    __builtin_amdgcn_sched_barrier(0);

    f32x4 accO[4];
    #pragma unroll
    for (int ii = 0; ii < 4; ++ii) accO[ii] = (f32x4){0.f, 0.f, 0.f, 0.f};
    #pragma unroll
    for (int ks = 0; ks < 2; ++ks) {
      vec8s aV = *(const vec8s*)(vg + l15 * 64 + ks * 32 + koct * 8);
      #pragma unroll
      for (int ii = 0; ii < 4; ++ii) {
        vec8s bP;
        const uint16_t* src = swPT + (ii * 16 + l15) * 68 + ks * 32 + koct * 8;
        *(uint2*)&bP         = *(const uint2*)(src);
        *((uint2*)&bP + 1)   = *(const uint2*)(src + 4);
        accO[ii] = __builtin_amdgcn_mfma_f32_16x16x32_bf16(aV, bP, accO[ii], 0, 0, 0);
      }
    }
    asm volatile("s_waitcnt lgkmcnt(0)" ::: "memory");
    __builtin_amdgcn_sched_barrier(0);

    #pragma unroll
    for (int ii = 0; ii < 4; ++ii) {
      #pragma unroll
      for (int r = 0; r < 4; ++r) {
        int dd = koct * 4 + r;
        swO[dd * 76 + ii * 16 + l15] = accO[ii][r] * sinv[ii];
      }
    }
    asm volatile("s_waitcnt lgkmcnt(0)" ::: "memory");
    __builtin_amdgcn_sched_barrier(0);
    #pragma unroll
    for (int e2 = 0; e2 < 2; ++e2) {
      int e = l + e2 * 64;
      int dd = e >> 3, row = e & 7;
      const float* orow = swO + dd * 76 + row * 8;
      float4 a = *(const float4*)(orow);
      float4 c = *(const float4*)(orow + 4);
      uint4 pk;
      pk.x = (uint32_t)f2bf(a.x) | ((uint32_t)f2bf(a.y) << 16);
      pk.y = (uint32_t)f2bf(a.z) | ((uint32_t)f2bf(a.w) << 16);
      pk.z = (uint32_t)f2bf(c.x) | ((uint32_t)f2bf(c.y) << 16);
      pk.w = (uint32_t)f2bf(c.z) | ((uint32_t)f2bf(c.w) << 16);
      *(uint4*)(outp + (size_t)(b * 256 + n * 16 + dd) * HW + wbase + row * 128) = pk;
    }
    asm volatile("s_waitcnt lgkmcnt(0)" ::: "memory");
    __builtin_amdgcn_sched_barrier(0);
  }
}

// ---------------------------------------------------------------------------
// combined = avgpool_v(attn) + avgpool_h(attn) + local (unchanged from r9).
// ---------------------------------------------------------------------------
__global__ __launch_bounds__(256) void k_pool(
    const uint16_t* __restrict__ attnb, float* __restrict__ loc)
{
  __shared__ __align__(16) float sP[71][136];
  const int t = threadIdx.x;
  const int plane = blockIdx.x >> 1;
  const int h0 = (blockIdx.x & 1) * 64;
  const size_t pbase = (size_t)plane * HW;
  #pragma unroll
  for (int k = 0; k < 5; ++k) {
    int idx = t + k * 256;
    if (idx < 71 * 16) {
      int lr = idx >> 4, m = idx & 15;
      int g = h0 - 3 + lr;
      float f[8] = {0.f,0.f,0.f,0.f,0.f,0.f,0.f,0.f};
      if (g >= 0 && g <= 127) {
        uint4 v4 = *(const uint4*)(attnb + pbase + (size_t)g * 128 + m * 8);
        unpack2(v4.x, f[0], f[1]); unpack2(v4.y, f[2], f[3]);
        unpack2(v4.z, f[4], f[5]); unpack2(v4.w, f[6], f[7]);
      }
      float* dst = &sP[lr][4 + m * 8];
      *(float4*)dst       = (float4){f[0], f[1], f[2], f[3]};
      *(float4*)(dst + 4) = (float4){f[4], f[5], f[6], f[7]};
    }
  }
  #pragma unroll
  for (int k = 0; k < 3; ++k) {
    int idx = t + k * 256;
    if (idx < 71 * 8) {
      int lr = idx >> 3, e = idx & 7;
      int c = (e < 4) ? e : (128 + e);
      sP[lr][c] = 0.f;
    }
  }
  __syncthreads();

  const int q  = t & 31;
  const int r0 = (t >> 5) * 8;
  const int w0 = q * 4;
  float4 av = {0.f, 0.f, 0.f, 0.f};
  #pragma unroll
  for (int o = 0; o < 8; ++o) {
    float4 v = *(const float4*)&sP[r0 + o][4 + w0];
    av.x += v.x; av.y += v.y; av.z += v.z; av.w += v.w;
  }
  #pragma unroll
  for (int rr = 0; rr < 8; ++rr) {
    const int lh = r0 + rr;
    const int h = h0 + lh;
    float4 a = av;
    if (h >= 124) {
      float4 cfix = *(const float4*)&sP[126 - 64 + 3][4 + w0];
      a.x += cfix.x; a.y += cfix.y; a.z += cfix.z; a.w += cfix.w;
    }
    float4 hv0 = *(const float4*)&sP[lh + 3][w0];
    float4 hv1 = *(const float4*)&sP[lh + 3][w0 + 4];
    float4 hv2 = *(const float4*)&sP[lh + 3][w0 + 8];
    float s0 = hv0.y + hv0.z + hv0.w + hv1.x + hv1.y + hv1.z + hv1.w + hv2.x;
    float s1 = s0 - hv0.y + hv2.y;
    float s2 = s1 - hv0.z + hv2.z;
    float s3 = s2 - hv0.w + hv2.w;
    if (q == 31) {
      float cfix = sP[lh + 3][130];
      s0 += cfix; s1 += cfix; s2 += cfix; s3 += cfix;
    }
    const size_t gi = pbase + (size_t)h * 128 + w0;
    float4 lv = *(const float4*)(loc + gi);
    float4 o4;
    o4.x = fmaf(a.x + s0, 0.125f, lv.x);
    o4.y = fmaf(a.y + s1, 0.125f, lv.y);
    o4.z = fmaf(a.z + s2, 0.125f, lv.z);
    o4.w = fmaf(a.w + s3, 0.125f, lv.w);
    *(float4*)(loc + gi) = o4;
    if (rr < 7) {
      float4 vm = *(const float4*)&sP[lh][4 + w0];
      float4 vp = *(const float4*)&sP[lh + 8][4 + w0];
      av.x += vp.x - vm.x; av.y += vp.y - vm.y;
      av.z += vp.z - vm.z; av.w += vp.w - vm.w;
    }
  }
}

// ---------------------------------------------------------------------------
// Depthwise 8x8 conv (unchanged from r10).
// ---------------------------------------------------------------------------
__global__ __launch_bounds__(256) void k_dw(
    const float* __restrict__ comb, const float* __restrict__ wdw,
    float* __restrict__ out)
{
  __shared__ __align__(16) float sZ[71][136];
  __shared__ float sWd[64];
  const int t = threadIdx.x;
  const int plane = blockIdx.x >> 1;
  const int cch = plane & 255;
  const int h0 = (blockIdx.x & 1) * 64;
  const size_t pbase = (size_t)plane * HW;
  if (t < 64) sWd[t] = wdw[cch * 64 + t];
  #pragma unroll
  for (int k = 0; k < 5; ++k) {
    int idx = t + k * 256;
    if (idx < 71 * 16) {
      int lr = idx >> 4, m = idx & 15;
      int g = h0 - 3 + lr;
      float4 a = {0.f,0.f,0.f,0.f}, c = {0.f,0.f,0.f,0.f};
      if (g >= 0 && g <= 128) {
        int gr = (g == 128) ? 126 : g;
        const float* src = comb + pbase + (size_t)gr * 128 + m * 8;
        a = *(const float4*)(src);
        c = *(const float4*)(src + 4);
      }
      float* dst = &sZ[lr][4 + m * 8];
      *(float4*)dst       = a;
      *(float4*)(dst + 4) = c;
    }
  }
  if (t < 71) {
    int lr = t;
    int g = h0 - 3 + lr;
    float rv = 0.f;
    if (g >= 0 && g <= 128) {
      int gr = (g == 128) ? 126 : g;
      rv = comb[pbase + (size_t)gr * 128 + 126];
    }
    *(float4*)&sZ[lr][0] = (float4){0.f, 0.f, 0.f, 0.f};
    sZ[lr][132] = rv;
    sZ[lr][133] = 0.f; sZ[lr][134] = 0.f; sZ[lr][135] = 0.f;
  }
  __syncthreads();

  float wt[8][8];
  #pragma unroll
  for (int i = 0; i < 8; ++i) {
    *(float4*)&wt[i][0] = *(const float4*)&sWd[i * 8];
    *(float4*)&wt[i][4] = *(const float4*)&sWd[i * 8 + 4];
  }

  const int q  = t & 31;
  const int rg = t >> 5;
  const int w0 = q * 4;
  f32x4 acc[8];
  #pragma unroll
  for (int rr = 0; rr < 8; ++rr) acc[rr] = (f32x4){0.f,0.f,0.f,0.f};

  #pragma unroll
  for (int v = 0; v < 15; ++v) {
    const int lr = rg * 8 + v;
    float win[12];
    *(float4*)&win[0] = *(const float4*)&sZ[lr][w0];
    *(float4*)&win[4] = *(const float4*)&sZ[lr][w0 + 4];
    *(float4*)&win[8] = *(const float4*)&sZ[lr][w0 + 8];
    #pragma unroll
    for (int rr = 0; rr < 8; ++rr) {
      const int i = v - rr;
      if (i >= 0 && i < 8) {
        #pragma unroll
        for (int c = 0; c < 4; ++c) {
          float s = acc[rr][c];
          #pragma unroll
          for (int j = 0; j < 8; ++j)
            s = fmaf(wt[i][j], win[c + j + 1], s);
          acc[rr][c] = s;
        }
      }
    }
  }
  #pragma unroll
  for (int rr = 0; rr < 8; ++rr) {
    int h = h0 + rg * 8 + rr;
    float* dst = out + pbase + (size_t)h * 128 + w0;
    *(float4*)dst = (float4){acc[rr][0], acc[rr][1], acc[rr][2], acc[rr][3]};
  }
}

} // namespace

extern "C" void kernel_launch(void* const* d_in, const int* in_sizes, int n_in,
                              void* d_out, int out_size, void* d_ws, size_t ws_size,
                              hipStream_t stream)
{
  const float* x      = (const float*)d_in[0];
  const float* w_pre  = (const float*)d_in[1];
  const float* bn_pre = (const float*)d_in[2];
  const float* w_l1   = (const float*)d_in[3];
  const float* bn_l1  = (const float*)d_in[4];
  const float* w_l2   = (const float*)d_in[5];
  const float* bn_l2  = (const float*)d_in[6];
  const float* w_l3   = (const float*)d_in[7];
  const float* bn_l3  = (const float*)d_in[8];
  const float* w_qkv  = (const float*)d_in[9];
  const float* rpb    = (const float*)d_in[10];
  const float* w_dw   = (const float*)d_in[11];
  const float* w_pw   = (const float*)d_in[12];
  const float* bn_pj  = (const float*)d_in[13];
  float* out = (float*)d_out;

  char* base = (char*)d_ws;
  uint16_t* xT    = (uint16_t*)base;                          // 64 MiB NHWC bf16 x; later dwT
  uint16_t* preT  = (uint16_t*)(base + (size_t)67108864);     // 64 MiB NHWC bf16 pre; later attn out; later wpw_bf
  float*    bufB  = (float*)(base + (size_t)134217728);       // 128 MiB fp32 local/combined
  uint16_t* bufQ  = (uint16_t*)(base + (size_t)268435456);    // 192 MiB bf16 qkv windows; later dw out
  uint16_t* attnO = preT;
  float*    bufDw = (float*)bufQ;
  uint16_t* dwT   = xT;
  // bf16 weights: wpre/wqkv in d_out (free until step 8); wpw in preT (free after step 5)
  uint16_t* wpre_bf = (uint16_t*)out;
  uint16_t* wqkv_bf = wpre_bf + 65536;
  uint16_t* wpw_bf  = preT;

  dim3 blk(256);
  // W pre-conversion
  k_w2bf<<<dim3(32),  blk, 0, stream>>>(w_pre, wpre_bf, 65536);
  k_w2bf<<<dim3(96),  blk, 0, stream>>>(w_qkv, wqkv_bf, 196608);
  // 0. cast x -> NHWC bf16
  k_cast<<<dim3(1024), blk, 0, stream>>>(x, xT);
  // 1. pre 1x1 conv + bn -> NHWC bf16 (MFMA v2, bf16-W stage)
  k_gemm_v2<0, 2><<<dim3(1024), blk, 0, stream>>>(xT, wpre_bf, bn_pre, 256, preT, nullptr);
  // 2. dilated 3x3 convs + bn (MFMA) -> bufB fp32 NCHW
  k_dilconv_mfma<1, 86><<<dim3(32, 2, 8), blk, 0, stream>>>(preT, w_l1, bn_l1, bufB, 0, 0);
  k_dilconv_mfma<2, 86><<<dim3(32, 2, 8), blk, 0, stream>>>(preT, w_l2, bn_l2, bufB, 86, 80);
  k_dilconv_mfma<3, 84><<<dim3(32, 2, 8), blk, 0, stream>>>(preT, w_l3, bn_l3, bufB, 172, 160);
  // 3. qkv 1x1 conv -> bufQ window-layout bf16 (MFMA v2, bf16-W stage)
  k_gemm_v2<3, 6><<<dim3(1024), blk, 0, stream>>>(xT, wqkv_bf, nullptr, 768, bufQ, nullptr);
  // 4. windowed attention (MFMA) -> attnO bf16 NCHW (overwrites preT; safe)
  k_attn<<<dim3(256, 8), blk, 0, stream>>>(bufQ, rpb, attnO);
  // 5. pools + residual combine (in-place on bufB)
  k_pool<<<dim3(4096), blk, 0, stream>>>(attnO, bufB);
  // 5b. wpw -> bf16 into preT region (attnO dead after pool)
  k_w2bf<<<dim3(32), blk, 0, stream>>>(w_pw, wpw_bf, 65536);
  // 6. depthwise 8x8 -> bufDw fp32 NCHW (overwrites bufQ; safe)
  k_dw<<<dim3(4096), blk, 0, stream>>>(bufB, w_dw, bufDw);
  // 7. cast dw-out -> NHWC bf16 (overwrites xT; safe)
  k_cast<<<dim3(1024), blk, 0, stream>>>(bufDw, dwT);
  // 8. pw 1x1 conv + bn -> out fp32 NCHW (MFMA v2, bf16-W stage)
  k_gemm_v2<2, 2><<<dim3(1024), blk, 0, stream>>>(dwT, wpw_bf, bn_pj, 256, nullptr, out);

  (void)in_sizes; (void)n_in; (void)out_size; (void)ws_size;
}

// Round 13
// 720.234 us; speedup vs baseline: 1.1654x; 1.0132x over previous
//
#include <hip/hip_runtime.h>
#include <hip/hip_bf16.h>
#include <cstdint>
#include <cstddef>

namespace {

constexpr int HW = 16384;   // 128*128

typedef short vec8s __attribute__((ext_vector_type(8)));
typedef float f32x4 __attribute__((ext_vector_type(4)));

__device__ __forceinline__ float u2f(uint32_t u){ union { uint32_t u; float f; } v; v.u = u; return v.f; }
__device__ __forceinline__ uint32_t f2u(float f){ union { float f; uint32_t u; } v; v.f = f; return v.u; }
__device__ __forceinline__ uint16_t f2bf(float f){
  uint32_t u = f2u(f);
  u += 0x7fffu + ((u >> 16) & 1u);   // round-to-nearest-even
  return (uint16_t)(u >> 16);
}
__device__ __forceinline__ void unpack2(uint32_t w, float& lo, float& hi){
  lo = u2f(w << 16);
  hi = u2f(w & 0xffff0000u);
}

// ---------------------------------------------------------------------------
// Elementwise fp32 -> bf16 (weight pre-conversion). n multiple of 8.
// ---------------------------------------------------------------------------
__global__ __launch_bounds__(256) void k_w2bf(
    const float* __restrict__ src, uint16_t* __restrict__ dst, int n)
{
  int i = (blockIdx.x * 256 + threadIdx.x) * 8;
  if (i + 8 <= n) {
    float4 a = *(const float4*)(src + i);
    float4 b = *(const float4*)(src + i + 4);
    uint4 pk;
    pk.x = (uint32_t)f2bf(a.x) | ((uint32_t)f2bf(a.y) << 16);
    pk.y = (uint32_t)f2bf(a.z) | ((uint32_t)f2bf(a.w) << 16);
    pk.z = (uint32_t)f2bf(b.x) | ((uint32_t)f2bf(b.y) << 16);
    pk.w = (uint32_t)f2bf(b.z) | ((uint32_t)f2bf(b.w) << 16);
    *(uint4*)(dst + i) = pk;
  }
}

// ---------------------------------------------------------------------------
// Cast NCHW fp32 (256 ch) -> NHWC bf16. Block = one (b, row).
// ---------------------------------------------------------------------------
__global__ __launch_bounds__(256) void k_cast(
    const float* __restrict__ x, uint16_t* __restrict__ xT)
{
  __shared__ float sF[64][129];
  const int t = threadIdx.x;
  const int b = blockIdx.x >> 7;
  const int y = blockIdx.x & 127;
  const size_t rowoff = (size_t)y * 128;
  for (int cc = 0; cc < 4; ++cc) {
    const int cic0 = cc * 64;
    #pragma unroll
    for (int k = 0; k < 8; ++k) {
      int e = t + k * 256;
      int ci = e >> 5;
      int pxq = (e & 31) * 4;
      float4 v = *(const float4*)(x + (size_t)(b * 256 + cic0 + ci) * HW + rowoff + pxq);
      sF[ci][pxq] = v.x; sF[ci][pxq+1] = v.y; sF[ci][pxq+2] = v.z; sF[ci][pxq+3] = v.w;
    }
    __syncthreads();
    {
      int px = t >> 1, h = t & 1;
      __align__(16) uint16_t tmp[32];
      #pragma unroll
      for (int j = 0; j < 32; ++j) tmp[j] = f2bf(sF[h * 32 + j][px]);
      uint16_t* dst = xT + ((size_t)b * HW + rowoff + px) * 256 + cic0 + h * 32;
      *(uint4*)(dst)      = *(uint4*)&tmp[0];
      *(uint4*)(dst + 8)  = *(uint4*)&tmp[8];
      *(uint4*)(dst + 16) = *(uint4*)&tmp[16];
      *(uint4*)(dst + 24) = *(uint4*)&tmp[24];
    }
    __syncthreads();
  }
}

// ---------------------------------------------------------------------------
// 1x1 conv via bf16 MFMA, X-resident co-loop with pre-converted bf16 W
// (unchanged from r12).
// ---------------------------------------------------------------------------
template<int OUT_MODE, int NCO>
__global__ __launch_bounds__(256) void k_gemm_v2(
    const uint16_t* __restrict__ xT, const uint16_t* __restrict__ wbf,
    const float* __restrict__ bnp, int M,
    uint16_t* __restrict__ outb, float* __restrict__ outf)
{
  __shared__ __align__(16) uint16_t sX[128][260];
  __shared__ __align__(16) uint16_t sW[128][36];
  const int t = threadIdx.x;
  const int b    = blockIdx.x >> 7;
  const int tile = blockIdx.x & 127;
  const int l = t & 63, w = t >> 6;
  const int l15 = l & 15, koct = l >> 4;
  const int wc = w >> 1, wp = w & 1;

  {
    const int spx = t >> 1, sh = t & 1;
    int gpx;
    if constexpr (OUT_MODE == 3) {
      int win = tile * 2 + (spx >> 6);
      int p = spx & 63;
      gpx = ((win >> 4) * 8 + (p >> 3)) * 128 + (win & 15) * 8 + (p & 7);
    } else {
      gpx = tile * 128 + spx;
    }
    const uint16_t* src = xT + ((size_t)b * HW + gpx) * 256 + sh * 128;
    uint16_t* dst = &sX[spx][sh * 128];
    #pragma unroll
    for (int i = 0; i < 16; ++i)
      *(uint4*)(dst + i * 8) = *(const uint4*)(src + i * 8);
  }

  const int swc = t >> 1, swh = t & 1;
  uint4 wr0, wr1;
  {
    const uint16_t* p = wbf + (size_t)swc * 256 + swh * 16;
    wr0 = *(const uint4*)(p);
    wr1 = *(const uint4*)(p + 8);
  }
  __syncthreads();

  for (int cc = 0; cc < NCO; ++cc) {
    f32x4 acc[4][4];
    #pragma unroll
    for (int cf = 0; cf < 4; ++cf)
      #pragma unroll
      for (int pf = 0; pf < 4; ++pf) acc[cf][pf] = (f32x4){0.f,0.f,0.f,0.f};

    for (int kc = 0; kc < 8; ++kc) {
      if (cc | kc) __syncthreads();
      {
        uint16_t* dst = &sW[swc][swh * 16];
        *(uint4*)(dst)     = wr0;
        *(uint4*)(dst + 8) = wr1;
      }
      {
        int nkc = kc + 1, ncc = cc;
        if (nkc == 8) { nkc = 0; ncc = cc + 1; }
        if (ncc < NCO) {
          const uint16_t* p = wbf + (size_t)(ncc * 128 + swc) * 256 + nkc * 32 + swh * 16;
          wr0 = *(const uint4*)(p);
          wr1 = *(const uint4*)(p + 8);
        }
      }
      __syncthreads();
      vec8s bf[4];
      #pragma unroll
      for (int pf = 0; pf < 4; ++pf)
        bf[pf] = *(const vec8s*)&sX[wp * 64 + pf * 16 + l15][kc * 32 + koct * 8];
      #pragma unroll
      for (int cf = 0; cf < 4; ++cf) {
        vec8s af = *(const vec8s*)&sW[wc * 64 + cf * 16 + l15][koct * 8];
        #pragma unroll
        for (int pf = 0; pf < 4; ++pf)
          acc[cf][pf] = __builtin_amdgcn_mfma_f32_16x16x32_bf16(af, bf[pf], acc[cf][pf], 0, 0, 0);
      }
    }

    #pragma unroll
    for (int cf = 0; cf < 4; ++cf) {
      const int cbase = cc * 128 + wc * 64 + cf * 16 + koct * 4;
      float scv[4], shv[4];
      #pragma unroll
      for (int r = 0; r < 4; ++r) {
        scv[r] = 1.f; shv[r] = 0.f;
        if constexpr (OUT_MODE == 0 || OUT_MODE == 2) {
          int c = cbase + r;
          float g = bnp[c], be = bnp[M + c], mu = bnp[2 * M + c], va = bnp[3 * M + c];
          scv[r] = g * rsqrtf(va + 1e-5f);
          shv[r] = be - mu * scv[r];
        }
      }
      #pragma unroll
      for (int pf = 0; pf < 4; ++pf) {
        if constexpr (OUT_MODE == 0) {
          int px = tile * 128 + wp * 64 + pf * 16 + l15;
          __align__(8) uint16_t pk[4];
          #pragma unroll
          for (int r = 0; r < 4; ++r)
            pk[r] = f2bf(fmaf(acc[cf][pf][r], scv[r], shv[r]));
          *(uint2*)(outb + ((size_t)b * HW + px) * 256 + cbase) = *(uint2*)pk;
        } else if constexpr (OUT_MODE == 2) {
          int px = tile * 128 + wp * 64 + pf * 16 + l15;
          #pragma unroll
          for (int r = 0; r < 4; ++r)
            outf[(size_t)(b * M + cbase + r) * HW + px] =
                fmaf(acc[cf][pf][r], scv[r], shv[r]);
        } else {
          int win = tile * 2 + wp;
          int p = pf * 16 + l15;
          uint16_t* dstp = outb + ((size_t)(b * 256 + win) * 768 + cbase) * 64 + p;
          #pragma unroll
          for (int r = 0; r < 4; ++r)
            dstp[(size_t)r * 64] = f2bf(acc[cf][pf][r]);
        }
      }
    }
  }
}

// ---------------------------------------------------------------------------
// Dilated 3x3 conv + BN via bf16 MFMA implicit GEMM (unchanged from r3).
// ---------------------------------------------------------------------------
template<int DIL, int CG>
__global__ __launch_bounds__(256) void k_dilconv_mfma(
    const uint16_t* __restrict__ preT, const float* __restrict__ wt,
    const float* __restrict__ bnp, float* __restrict__ out,
    int cb, int cb_al)
{
  constexpr int R = 8 + 2 * DIL;
  constexpr int C = 64 + 2 * DIL;
  constexpr int NPOS = R * C;
  constexpr int NIT = (NPOS + 255) / 256;
  __shared__ __align__(16) uint16_t sX[NPOS * 16];
  __shared__ __align__(16) uint16_t sW[10 * 50 * 16];

  const int t = threadIdx.x;
  const int rt    = blockIdx.x >> 1;
  const int ctile = blockIdx.x & 1;
  const int ct2   = blockIdx.y;
  const int b     = blockIdx.z;
  const int y0 = rt * 8, x0 = ctile * 64;
  const int l = t & 63, w = t >> 6;
  const int l15 = l & 15, oct = (l >> 4) & 1, half = l >> 5;
  const int rbase = w * 2;

  f32x4 acc[3][8];
  #pragma unroll
  for (int cf = 0; cf < 3; ++cf)
    #pragma unroll
    for (int q = 0; q < 8; ++q) acc[cf][q] = (f32x4){0.f,0.f,0.f,0.f};

  for (int kc = 0; kc < 6; ++kc) {
    #pragma unroll
    for (int i = 0; i < 3; ++i) {
      int pair = t + i * 256;
      int co = pair >> 4, ci = pair & 15;
      int cog = ct2 * 48 + co;
      int c = cb_al + kc * 16 + ci;
      bool ok = (cog < CG) && (c >= cb) && (c < cb + CG);
      size_t widx = ok ? ((size_t)cog * (size_t)CG + (size_t)(c - cb)) * 9u
                       : (size_t)0;
      const float* wp = wt + widx;
      uint16_t* dst = &sW[co * 16 + ci];
      #pragma unroll
      for (int tap = 0; tap < 9; ++tap)
        dst[tap * 800] = ok ? f2bf(wp[tap]) : (uint16_t)0;
      dst[9 * 800] = 0;
    }
    #pragma unroll
    for (int i = 0; i < NIT; ++i) {
      int p = t + i * 256;
      if (p < NPOS) {
        int row = p / C, col = p % C;
        int gy = y0 + row - DIL, gx = x0 + col - DIL;
        uint4 va = {0,0,0,0}, vb = {0,0,0,0};
        if ((unsigned)gy < 128u && (unsigned)gx < 128u) {
          const uint4* src = (const uint4*)(preT +
              (((size_t)b * HW + gy * 128 + gx) * 256 + cb_al + kc * 16));
          va = src[0]; vb = src[1];
        }
        uint4* dst = (uint4*)&sX[p * 16];
        dst[0] = va; dst[1] = vb;
      }
    }
    __syncthreads();

    #pragma unroll
    for (int s = 0; s < 5; ++s) {
      const int tap0 = 2 * s, tap1 = 2 * s + 1;
      const int dy0 = tap0 / 3, dx0 = tap0 % 3;
      const int dy1 = (tap1 <= 8) ? tap1 / 3 : 2;
      const int dx1 = (tap1 <= 8) ? tap1 % 3 : 2;
      const int dy = half ? dy1 : dy0;
      const int dx = half ? dx1 : dx0;
      const int atap = tap0 + half;
      vec8s a0 = *(const vec8s*)&sW[(atap * 50 + 0  + l15) * 16 + oct * 8];
      vec8s a1 = *(const vec8s*)&sW[(atap * 50 + 16 + l15) * 16 + oct * 8];
      vec8s a2 = *(const vec8s*)&sW[(atap * 50 + 32 + l15) * 16 + oct * 8];
      #pragma unroll
      for (int rs = 0; rs < 2; ++rs) {
        const int rowin = rbase + rs + dy * DIL;
        #pragma unroll
        for (int c4 = 0; c4 < 4; ++c4) {
          const int colin = c4 * 16 + l15 + dx * DIL;
          vec8s bf = *(const vec8s*)&sX[(rowin * C + colin) * 16 + oct * 8];
          acc[0][rs*4+c4] = __builtin_amdgcn_mfma_f32_16x16x32_bf16(a0, bf, acc[0][rs*4+c4], 0, 0, 0);
          acc[1][rs*4+c4] = __builtin_amdgcn_mfma_f32_16x16x32_bf16(a1, bf, acc[1][rs*4+c4], 0, 0, 0);
          acc[2][rs*4+c4] = __builtin_amdgcn_mfma_f32_16x16x32_bf16(a2, bf, acc[2][rs*4+c4], 0, 0, 0);
        }
      }
    }
    __syncthreads();
  }

  const int row4 = (l >> 4);
  #pragma unroll
  for (int cf = 0; cf < 3; ++cf) {
    #pragma unroll
    for (int r = 0; r < 4; ++r) {
      int c_loc = ct2 * 48 + cf * 16 + row4 * 4 + r;
      if (c_loc < CG) {
        int cg = cb + c_loc;
        float g = bnp[c_loc], be = bnp[CG + c_loc];
        float mu = bnp[2 * CG + c_loc], va = bnp[3 * CG + c_loc];
        float scv = g * rsqrtf(va + 1e-5f);
        float shv = be - mu * scv;
        #pragma unroll
        for (int rs = 0; rs < 2; ++rs) {
          int y = y0 + rbase + rs;
          #pragma unroll
          for (int c4 = 0; c4 < 4; ++c4) {
            int x = x0 + c4 * 16 + l15;
            out[(size_t)(b * 256 + cg) * HW + y * 128 + x] =
                fmaf(acc[cf][rs*4+c4][r], scv, shv);
          }
        }
      }
    }
  }
}

// ---------------------------------------------------------------------------
// Windowed attention v3: wave-autonomous MFMA + LDS overlay + SW pipeline.
// Per-wave LDS: KT[0,2560e) QT[2560,5120e) bias(f32)[5120,5632e).
// PT (bf16 [64][68], 4352e) and O (f32, 2408e) OVERLAY the KT/QT region
// (both consumed into regs before overwrite; r8-proven fencing pattern).
// K/Q/bias for head n+4 prefetched during head n's compute; V hoisted to
// regs right after staging (PV has no global dependency).
// ---------------------------------------------------------------------------
__global__ __launch_bounds__(256) void k_attn(
    const uint16_t* __restrict__ qkvW, const float* __restrict__ rpb,
    uint16_t* __restrict__ outp)
{
  __shared__ __align__(16) uint16_t sAll[4][5632];
  const int t = threadIdx.x;
  const int l = t & 63, w = t >> 6;
  const int l15 = l & 15, koct = l >> 4;
  const int b = blockIdx.y;
  const int win = blockIdx.x;
  const int wy = win >> 4, wx = win & 15;
  const int wbase = (wy * 8) * 128 + wx * 8;
  const uint16_t* base = qkvW + (size_t)(b * 256 + win) * 49152;
  uint16_t* swKT = &sAll[w][0];
  uint16_t* swQT = &sAll[w][2560];
  uint16_t* swPT = &sAll[w][0];          // overlay on KT/QT
  float*    swO  = (float*)&sAll[w][0];  // overlay on PT
  float*    swB  = (float*)&sAll[w][5120];

  // ---- prologue prefetch: head n0 = w ----
  const uint16_t* qg = base + (size_t)(w * 16) * 64;
  const uint16_t* kg = qg + 256 * 64;
  const uint16_t* vg = qg + 512 * 64;
  uint32_t kp[8], qp[8];
  float breg[4];
  #pragma unroll
  for (int m = 0; m < 8; ++m) {
    uint32_t k0 = kg[(2 * m) * 64 + l], k1 = kg[(2 * m + 1) * 64 + l];
    uint32_t q0 = qg[(2 * m) * 64 + l], q1 = qg[(2 * m + 1) * 64 + l];
    kp[m] = k0 | (k1 << 16);
    qp[m] = q0 | (q1 << 16);
  }
  #pragma unroll
  for (int m = 0; m < 4; ++m) {
    int e = l + m * 64;
    breg[m] = (e < 225) ? rpb[e * 16 + w] : 0.f;
  }

  for (int it = 0; it < 4; ++it) {
    const int n = w + it * 4;
    // ---- stage bias + KT/QT (+pad zeros) from prefetched regs ----
    #pragma unroll
    for (int m = 0; m < 4; ++m) {
      int e = l + m * 64;
      if (e < 225) swB[e] = breg[m];
    }
    {
      uint4 z = {0, 0, 0, 0};
      *(uint4*)(swKT + l * 40)      = *(uint4*)&kp[0];
      *(uint4*)(swKT + l * 40 + 8)  = *(uint4*)&kp[4];
      *(uint4*)(swKT + l * 40 + 16) = z;
      *(uint4*)(swKT + l * 40 + 24) = z;
      *(uint4*)(swQT + l * 40)      = *(uint4*)&qp[0];
      *(uint4*)(swQT + l * 40 + 8)  = *(uint4*)&qp[4];
      *(uint4*)(swQT + l * 40 + 16) = z;
      *(uint4*)(swQT + l * 40 + 24) = z;
    }
    // ---- hoist V (current head) to regs; prefetch K/Q/bias (next head) ----
    vec8s vA0 = *(const vec8s*)(vg + l15 * 64 + koct * 8);
    vec8s vA1 = *(const vec8s*)(vg + l15 * 64 + 32 + koct * 8);
    if (it < 3) {
      const uint16_t* qg2 = qg + 4096;
      const uint16_t* kg2 = kg + 4096;
      #pragma unroll
      for (int m = 0; m < 8; ++m) {
        uint32_t k0 = kg2[(2 * m) * 64 + l], k1 = kg2[(2 * m + 1) * 64 + l];
        uint32_t q0 = qg2[(2 * m) * 64 + l], q1 = qg2[(2 * m + 1) * 64 + l];
        kp[m] = k0 | (k1 << 16);
        qp[m] = q0 | (q1 << 16);
      }
      #pragma unroll
      for (int m = 0; m < 4; ++m) {
        int e = l + m * 64;
        breg[m] = (e < 225) ? rpb[e * 16 + n + 4] : 0.f;
      }
    }
    asm volatile("s_waitcnt lgkmcnt(0)" ::: "memory");
    __builtin_amdgcn_sched_barrier(0);

    // ---- QK^T: accS[ti][tj] = S tile [j 16][i 16] ----
    vec8s aK[4], bQ[4];
    #pragma unroll
    for (int tt = 0; tt < 4; ++tt) {
      aK[tt] = *(const vec8s*)(swKT + (tt * 16 + l15) * 40 + koct * 8);
      bQ[tt] = *(const vec8s*)(swQT + (tt * 16 + l15) * 40 + koct * 8);
    }
    f32x4 accS[4][4];
    #pragma unroll
    for (int ti = 0; ti < 4; ++ti)
      #pragma unroll
      for (int tj = 0; tj < 4; ++tj)
        accS[ti][tj] = __builtin_amdgcn_mfma_f32_16x16x32_bf16(
            aK[tj], bQ[ti], (f32x4){0.f, 0.f, 0.f, 0.f}, 0, 0, 0);

    // ---- bias + softmax ----
    float p[4][16], sinv[4];
    #pragma unroll
    for (int ti = 0; ti < 4; ++ti) {
      const int i = ti * 16 + l15;
      const int irow = i >> 3, icol = i & 7;
      #pragma unroll
      for (int tj = 0; tj < 4; ++tj) {
        #pragma unroll
        for (int r = 0; r < 4; ++r) {
          int j = tj * 16 + koct * 4 + r;
          int rel = (irow - (j >> 3) + 7) * 15 + (icol - (j & 7) + 7);
          p[ti][tj * 4 + r] = fmaf(accS[ti][tj][r], 0.25f, swB[rel]);
        }
      }
      float mx = p[ti][0];
      #pragma unroll
      for (int u = 1; u < 16; ++u) mx = fmaxf(mx, p[ti][u]);
      mx = fmaxf(mx, __shfl_xor(mx, 16));
      mx = fmaxf(mx, __shfl_xor(mx, 32));
      float s = 0.f;
      #pragma unroll
      for (int u = 0; u < 16; ++u) { p[ti][u] = __expf(p[ti][u] - mx); s += p[ti][u]; }
      s += __shfl_xor(s, 16);
      s += __shfl_xor(s, 32);
      sinv[ti] = 1.f / s;
    }

    // ---- pack P -> PT[i][j] bf16 (overlay; KT/QT already in regs) ----
    #pragma unroll
    for (int ti = 0; ti < 4; ++ti) {
      uint16_t* rowp = swPT + (ti * 16 + l15) * 68 + koct * 4;
      #pragma unroll
      for (int tj = 0; tj < 4; ++tj) {
        uint32_t u0 = (uint32_t)f2bf(p[ti][tj * 4 + 0]) | ((uint32_t)f2bf(p[ti][tj * 4 + 1]) << 16);
        uint32_t u1 = (uint32_t)f2bf(p[ti][tj * 4 + 2]) | ((uint32_t)f2bf(p[ti][tj * 4 + 3]) << 16);
        *(uint32_t*)(rowp + tj * 16)     = u0;
        *(uint32_t*)(rowp + tj * 16 + 2) = u1;
      }
    }
    asm volatile("s_waitcnt lgkmcnt(0)" ::: "memory");
    __builtin_amdgcn_sched_barrier(0);

    // ---- PV: A = V regs (hoisted), B = P-frags from LDS ----
    f32x4 accO[4];
    #pragma unroll
    for (int ii = 0; ii < 4; ++ii) accO[ii] = (f32x4){0.f, 0.f, 0.f, 0.f};
    #pragma unroll
    for (int ks = 0; ks < 2; ++ks) {
      vec8s aV = ks ? vA1 : vA0;
      #pragma unroll
      for (int ii = 0; ii < 4; ++ii) {
        vec8s bP;
        const uint16_t* src = swPT + (ii * 16 + l15) * 68 + ks * 32 + koct * 8;
        *(uint2*)&bP       = *(const uint2*)(src);
        *((uint2*)&bP + 1) = *(const uint2*)(src + 4);
        accO[ii] = __builtin_amdgcn_mfma_f32_16x16x32_bf16(aV, bP, accO[ii], 0, 0, 0);
      }
    }
    asm volatile("s_waitcnt lgkmcnt(0)" ::: "memory");
    __builtin_amdgcn_sched_barrier(0);

    // ---- O stage (overlay on PT) + 16B-run NCHW stores ----
    #pragma unroll
    for (int ii = 0; ii < 4; ++ii) {
      #pragma unroll
      for (int r = 0; r < 4; ++r) {
        int dd = koct * 4 + r;
        swO[dd * 76 + ii * 16 + l15] = accO[ii][r] * sinv[ii];
      }
    }
    asm volatile("s_waitcnt lgkmcnt(0)" ::: "memory");
    __builtin_amdgcn_sched_barrier(0);
    #pragma unroll
    for (int e2 = 0; e2 < 2; ++e2) {
      int e = l + e2 * 64;
      int dd = e >> 3, row = e & 7;
      const float* orow = swO + dd * 76 + row * 8;
      float4 a = *(const float4*)(orow);
      float4 c = *(const float4*)(orow + 4);
      uint4 pk;
      pk.x = (uint32_t)f2bf(a.x) | ((uint32_t)f2bf(a.y) << 16);
      pk.y = (uint32_t)f2bf(a.z) | ((uint32_t)f2bf(a.w) << 16);
      pk.z = (uint32_t)f2bf(c.x) | ((uint32_t)f2bf(c.y) << 16);
      pk.w = (uint32_t)f2bf(c.z) | ((uint32_t)f2bf(c.w) << 16);
      *(uint4*)(outp + (size_t)(b * 256 + n * 16 + dd) * HW + wbase + row * 128) = pk;
    }
    asm volatile("s_waitcnt lgkmcnt(0)" ::: "memory");
    __builtin_amdgcn_sched_barrier(0);
    qg += 4096; kg += 4096; vg += 4096;
  }
}

// ---------------------------------------------------------------------------
// combined = avgpool_v(attn) + avgpool_h(attn) + local (unchanged from r9).
// ---------------------------------------------------------------------------
__global__ __launch_bounds__(256) void k_pool(
    const uint16_t* __restrict__ attnb, float* __restrict__ loc)
{
  __shared__ __align__(16) float sP[71][136];
  const int t = threadIdx.x;
  const int plane = blockIdx.x >> 1;
  const int h0 = (blockIdx.x & 1) * 64;
  const size_t pbase = (size_t)plane * HW;
  #pragma unroll
  for (int k = 0; k < 5; ++k) {
    int idx = t + k * 256;
    if (idx < 71 * 16) {
      int lr = idx >> 4, m = idx & 15;
      int g = h0 - 3 + lr;
      float f[8] = {0.f,0.f,0.f,0.f,0.f,0.f,0.f,0.f};
      if (g >= 0 && g <= 127) {
        uint4 v4 = *(const uint4*)(attnb + pbase + (size_t)g * 128 + m * 8);
        unpack2(v4.x, f[0], f[1]); unpack2(v4.y, f[2], f[3]);
        unpack2(v4.z, f[4], f[5]); unpack2(v4.w, f[6], f[7]);
      }
      float* dst = &sP[lr][4 + m * 8];
      *(float4*)dst       = (float4){f[0], f[1], f[2], f[3]};
      *(float4*)(dst + 4) = (float4){f[4], f[5], f[6], f[7]};
    }
  }
  #pragma unroll
  for (int k = 0; k < 3; ++k) {
    int idx = t + k * 256;
    if (idx < 71 * 8) {
      int lr = idx >> 3, e = idx & 7;
      int c = (e < 4) ? e : (128 + e);
      sP[lr][c] = 0.f;
    }
  }
  __syncthreads();

  const int q  = t & 31;
  const int r0 = (t >> 5) * 8;
  const int w0 = q * 4;
  float4 av = {0.f, 0.f, 0.f, 0.f};
  #pragma unroll
  for (int o = 0; o < 8; ++o) {
    float4 v = *(const float4*)&sP[r0 + o][4 + w0];
    av.x += v.x; av.y += v.y; av.z += v.z; av.w += v.w;
  }
  #pragma unroll
  for (int rr = 0; rr < 8; ++rr) {
    const int lh = r0 + rr;
    const int h = h0 + lh;
    float4 a = av;
    if (h >= 124) {
      float4 cfix = *(const float4*)&sP[126 - 64 + 3][4 + w0];
      a.x += cfix.x; a.y += cfix.y; a.z += cfix.z; a.w += cfix.w;
    }
    float4 hv0 = *(const float4*)&sP[lh + 3][w0];
    float4 hv1 = *(const float4*)&sP[lh + 3][w0 + 4];
    float4 hv2 = *(const float4*)&sP[lh + 3][w0 + 8];
    float s0 = hv0.y + hv0.z + hv0.w + hv1.x + hv1.y + hv1.z + hv1.w + hv2.x;
    float s1 = s0 - hv0.y + hv2.y;
    float s2 = s1 - hv0.z + hv2.z;
    float s3 = s2 - hv0.w + hv2.w;
    if (q == 31) {
      float cfix = sP[lh + 3][130];
      s0 += cfix; s1 += cfix; s2 += cfix; s3 += cfix;
    }
    const size_t gi = pbase + (size_t)h * 128 + w0;
    float4 lv = *(const float4*)(loc + gi);
    float4 o4;
    o4.x = fmaf(a.x + s0, 0.125f, lv.x);
    o4.y = fmaf(a.y + s1, 0.125f, lv.y);
    o4.z = fmaf(a.z + s2, 0.125f, lv.z);
    o4.w = fmaf(a.w + s3, 0.125f, lv.w);
    *(float4*)(loc + gi) = o4;
    if (rr < 7) {
      float4 vm = *(const float4*)&sP[lh][4 + w0];
      float4 vp = *(const float4*)&sP[lh + 8][4 + w0];
      av.x += vp.x - vm.x; av.y += vp.y - vm.y;
      av.z += vp.z - vm.z; av.w += vp.w - vm.w;
    }
  }
}

// ---------------------------------------------------------------------------
// Depthwise 8x8 conv (unchanged from r10).
// ---------------------------------------------------------------------------
__global__ __launch_bounds__(256) void k_dw(
    const float* __restrict__ comb, const float* __restrict__ wdw,
    float* __restrict__ out)
{
  __shared__ __align__(16) float sZ[71][136];
  __shared__ float sWd[64];
  const int t = threadIdx.x;
  const int plane = blockIdx.x >> 1;
  const int cch = plane & 255;
  const int h0 = (blockIdx.x & 1) * 64;
  const size_t pbase = (size_t)plane * HW;
  if (t < 64) sWd[t] = wdw[cch * 64 + t];
  #pragma unroll
  for (int k = 0; k < 5; ++k) {
    int idx = t + k * 256;
    if (idx < 71 * 16) {
      int lr = idx >> 4, m = idx & 15;
      int g = h0 - 3 + lr;
      float4 a = {0.f,0.f,0.f,0.f}, c = {0.f,0.f,0.f,0.f};
      if (g >= 0 && g <= 128) {
        int gr = (g == 128) ? 126 : g;
        const float* src = comb + pbase + (size_t)gr * 128 + m * 8;
        a = *(const float4*)(src);
        c = *(const float4*)(src + 4);
      }
      float* dst = &sZ[lr][4 + m * 8];
      *(float4*)dst       = a;
      *(float4*)(dst + 4) = c;
    }
  }
  if (t < 71) {
    int lr = t;
    int g = h0 - 3 + lr;
    float rv = 0.f;
    if (g >= 0 && g <= 128) {
      int gr = (g == 128) ? 126 : g;
      rv = comb[pbase + (size_t)gr * 128 + 126];
    }
    *(float4*)&sZ[lr][0] = (float4){0.f, 0.f, 0.f, 0.f};
    sZ[lr][132] = rv;
    sZ[lr][133] = 0.f; sZ[lr][134] = 0.f; sZ[lr][135] = 0.f;
  }
  __syncthreads();

  float wt[8][8];
  #pragma unroll
  for (int i = 0; i < 8; ++i) {
    *(float4*)&wt[i][0] = *(const float4*)&sWd[i * 8];
    *(float4*)&wt[i][4] = *(const float4*)&sWd[i * 8 + 4];
  }

  const int q  = t & 31;
  const int rg = t >> 5;
  const int w0 = q * 4;
  f32x4 acc[8];
  #pragma unroll
  for (int rr = 0; rr < 8; ++rr) acc[rr] = (f32x4){0.f,0.f,0.f,0.f};

  #pragma unroll
  for (int v = 0; v < 15; ++v) {
    const int lr = rg * 8 + v;
    float win[12];
    *(float4*)&win[0] = *(const float4*)&sZ[lr][w0];
    *(float4*)&win[4] = *(const float4*)&sZ[lr][w0 + 4];
    *(float4*)&win[8] = *(const float4*)&sZ[lr][w0 + 8];
    #pragma unroll
    for (int rr = 0; rr < 8; ++rr) {
      const int i = v - rr;
      if (i >= 0 && i < 8) {
        #pragma unroll
        for (int c = 0; c < 4; ++c) {
          float s = acc[rr][c];
          #pragma unroll
          for (int j = 0; j < 8; ++j)
            s = fmaf(wt[i][j], win[c + j + 1], s);
          acc[rr][c] = s;
        }
      }
    }
  }
  #pragma unroll
  for (int rr = 0; rr < 8; ++rr) {
    int h = h0 + rg * 8 + rr;
    float* dst = out + pbase + (size_t)h * 128 + w0;
    *(float4*)dst = (float4){acc[rr][0], acc[rr][1], acc[rr][2], acc[rr][3]};
  }
}

} // namespace

extern "C" void kernel_launch(void* const* d_in, const int* in_sizes, int n_in,
                              void* d_out, int out_size, void* d_ws, size_t ws_size,
                              hipStream_t stream)
{
  const float* x      = (const float*)d_in[0];
  const float* w_pre  = (const float*)d_in[1];
  const float* bn_pre = (const float*)d_in[2];
  const float* w_l1   = (const float*)d_in[3];
  const float* bn_l1  = (const float*)d_in[4];
  const float* w_l2   = (const float*)d_in[5];
  const float* bn_l2  = (const float*)d_in[6];
  const float* w_l3   = (const float*)d_in[7];
  const float* bn_l3  = (const float*)d_in[8];
  const float* w_qkv  = (const float*)d_in[9];
  const float* rpb    = (const float*)d_in[10];
  const float* w_dw   = (const float*)d_in[11];
  const float* w_pw   = (const float*)d_in[12];
  const float* bn_pj  = (const float*)d_in[13];
  float* out = (float*)d_out;

  char* base = (char*)d_ws;
  uint16_t* xT    = (uint16_t*)base;                          // 64 MiB NHWC bf16 x; later dwT
  uint16_t* preT  = (uint16_t*)(base + (size_t)67108864);     // 64 MiB NHWC bf16 pre; later attn out; later wpw_bf
  float*    bufB  = (float*)(base + (size_t)134217728);       // 128 MiB fp32 local/combined
  uint16_t* bufQ  = (uint16_t*)(base + (size_t)268435456);    // 192 MiB bf16 qkv windows; later dw out
  uint16_t* attnO = preT;
  float*    bufDw = (float*)bufQ;
  uint16_t* dwT   = xT;
  uint16_t* wpre_bf = (uint16_t*)out;
  uint16_t* wqkv_bf = wpre_bf + 65536;
  uint16_t* wpw_bf  = preT;

  dim3 blk(256);
  // W pre-conversion
  k_w2bf<<<dim3(32),  blk, 0, stream>>>(w_pre, wpre_bf, 65536);
  k_w2bf<<<dim3(96),  blk, 0, stream>>>(w_qkv, wqkv_bf, 196608);
  // 0. cast x -> NHWC bf16
  k_cast<<<dim3(1024), blk, 0, stream>>>(x, xT);
  // 1. pre 1x1 conv + bn -> NHWC bf16 (MFMA v2, bf16-W stage)
  k_gemm_v2<0, 2><<<dim3(1024), blk, 0, stream>>>(xT, wpre_bf, bn_pre, 256, preT, nullptr);
  // 2. dilated 3x3 convs + bn (MFMA) -> bufB fp32 NCHW
  k_dilconv_mfma<1, 86><<<dim3(32, 2, 8), blk, 0, stream>>>(preT, w_l1, bn_l1, bufB, 0, 0);
  k_dilconv_mfma<2, 86><<<dim3(32, 2, 8), blk, 0, stream>>>(preT, w_l2, bn_l2, bufB, 86, 80);
  k_dilconv_mfma<3, 84><<<dim3(32, 2, 8), blk, 0, stream>>>(preT, w_l3, bn_l3, bufB, 172, 160);
  // 3. qkv 1x1 conv -> bufQ window-layout bf16 (MFMA v2, bf16-W stage)
  k_gemm_v2<3, 6><<<dim3(1024), blk, 0, stream>>>(xT, wqkv_bf, nullptr, 768, bufQ, nullptr);
  // 4. windowed attention (MFMA v3: overlay + pipeline) -> attnO bf16 NCHW
  k_attn<<<dim3(256, 8), blk, 0, stream>>>(bufQ, rpb, attnO);
  // 5. pools + residual combine (in-place on bufB)
  k_pool<<<dim3(4096), blk, 0, stream>>>(attnO, bufB);
  // 5b. wpw -> bf16 into preT region (attnO dead after pool)
  k_w2bf<<<dim3(32), blk, 0, stream>>>(w_pw, wpw_bf, 65536);
  // 6. depthwise 8x8 -> bufDw fp32 NCHW (overwrites bufQ; safe)
  k_dw<<<dim3(4096), blk, 0, stream>>>(bufB, w_dw, bufDw);
  // 7. cast dw-out -> NHWC bf16 (overwrites xT; safe)
  k_cast<<<dim3(1024), blk, 0, stream>>>(bufDw, dwT);
  // 8. pw 1x1 conv + bn -> out fp32 NCHW (MFMA v2, bf16-W stage)
  k_gemm_v2<2, 2><<<dim3(1024), blk, 0, stream>>>(dwT, wpw_bf, bn_pj, 256, nullptr, out);

  (void)in_sizes; (void)n_in; (void)out_size; (void)ws_size;
}

// Round 14
// 642.250 us; speedup vs baseline: 1.3069x; 1.1214x over previous
//
#include <hip/hip_runtime.h>
#include <hip/hip_bf16.h>
#include <cstdint>
#include <cstddef>

namespace {

constexpr int HW = 16384;   // 128*128

typedef short vec8s __attribute__((ext_vector_type(8)));
typedef float f32x4 __attribute__((ext_vector_type(4)));

__device__ __forceinline__ float u2f(uint32_t u){ union { uint32_t u; float f; } v; v.u = u; return v.f; }
__device__ __forceinline__ uint32_t f2u(float f){ union { float f; uint32_t u; } v; v.f = f; return v.u; }
__device__ __forceinline__ uint16_t f2bf(float f){
  uint32_t u = f2u(f);
  u += 0x7fffu + ((u >> 16) & 1u);   // round-to-nearest-even
  return (uint16_t)(u >> 16);
}
__device__ __forceinline__ void unpack2(uint32_t w, float& lo, float& hi){
  lo = u2f(w << 16);
  hi = u2f(w & 0xffff0000u);
}

// ---------------------------------------------------------------------------
// Elementwise fp32 -> bf16 (weight pre-conversion). n multiple of 8.
// ---------------------------------------------------------------------------
__global__ __launch_bounds__(256) void k_w2bf(
    const float* __restrict__ src, uint16_t* __restrict__ dst, int n)
{
  int i = (blockIdx.x * 256 + threadIdx.x) * 8;
  if (i + 8 <= n) {
    float4 a = *(const float4*)(src + i);
    float4 b = *(const float4*)(src + i + 4);
    uint4 pk;
    pk.x = (uint32_t)f2bf(a.x) | ((uint32_t)f2bf(a.y) << 16);
    pk.y = (uint32_t)f2bf(a.z) | ((uint32_t)f2bf(a.w) << 16);
    pk.z = (uint32_t)f2bf(b.x) | ((uint32_t)f2bf(b.y) << 16);
    pk.w = (uint32_t)f2bf(b.z) | ((uint32_t)f2bf(b.w) << 16);
    *(uint4*)(dst + i) = pk;
  }
}

// ---------------------------------------------------------------------------
// 1x1 conv via bf16 MFMA, X-resident co-loop; stages DIRECTLY from NCHW
// fp32 input (inline f2bf, no separate cast kernel). W pre-converted bf16.
// WINM: X-tile pixel enumeration is window-major (2 windows per tile).
// OUT_MODE 2: NCHW fp32 + BN (pw -> d_out), linear px.
// OUT_MODE 4: FUSED pre+qkv. W = [wpre(256) ; wqkv(768)] rows. cc<2 ->
//   pre NHWC bf16 + BN at win-major gpx; cc>=2 -> qkv window layout.
// ---------------------------------------------------------------------------
template<int OUT_MODE, int NCO, bool WINM>
__global__ __launch_bounds__(256) void k_gemm_v4(
    const float* __restrict__ xf, const uint16_t* __restrict__ wbf,
    const float* __restrict__ bnp,
    uint16_t* __restrict__ outbPre, uint16_t* __restrict__ outbQkv,
    float* __restrict__ outf)
{
  __shared__ __align__(16) uint16_t sX[128][260];
  __shared__ __align__(16) uint16_t sW[128][36];
  const int t = threadIdx.x;
  const int b    = blockIdx.x >> 7;
  const int tile = blockIdx.x & 127;
  const int l = t & 63, w = t >> 6;
  const int l15 = l & 15, koct = l >> 4;
  const int wc = w >> 1, wp = w & 1;     // wave co-half / px-half

  // ---- stage X tile from NCHW fp32 (f2bf inline) ----
  {
    const int cig = t >> 5;            // 0..7
    const int pq  = (t & 31) * 4;      // local px 4-group
    int gpx;
    if constexpr (WINM) {
      int win = tile * 2 + (pq >> 6);
      int p = pq & 63;
      gpx = ((win >> 4) * 8 + (p >> 3)) * 128 + (win & 15) * 8 + (p & 7);
    } else {
      gpx = tile * 128 + pq;
    }
    const float* srcb = xf + (size_t)b * 256 * HW + gpx;
    #pragma unroll
    for (int cb8 = 0; cb8 < 32; ++cb8) {
      int ci = cb8 * 8 + cig;
      float4 v = *(const float4*)(srcb + (size_t)ci * HW);
      sX[pq][ci]     = f2bf(v.x);
      sX[pq + 1][ci] = f2bf(v.y);
      sX[pq + 2][ci] = f2bf(v.z);
      sX[pq + 3][ci] = f2bf(v.w);
    }
  }

  // ---- W prefetch (bf16): thread t -> co row t>>1, 16-ci half t&1 ----
  const int swc = t >> 1, swh = t & 1;
  uint4 wr0, wr1;
  {
    const uint16_t* p = wbf + (size_t)swc * 256 + swh * 16;
    wr0 = *(const uint4*)(p);
    wr1 = *(const uint4*)(p + 8);
  }
  __syncthreads();   // X resident

  for (int cc = 0; cc < NCO; ++cc) {
    f32x4 acc[4][4];
    #pragma unroll
    for (int cf = 0; cf < 4; ++cf)
      #pragma unroll
      for (int pf = 0; pf < 4; ++pf) acc[cf][pf] = (f32x4){0.f,0.f,0.f,0.f};

    for (int kc = 0; kc < 8; ++kc) {
      if (cc | kc) __syncthreads();
      {
        uint16_t* dst = &sW[swc][swh * 16];
        *(uint4*)(dst)     = wr0;
        *(uint4*)(dst + 8) = wr1;
      }
      {
        int nkc = kc + 1, ncc = cc;
        if (nkc == 8) { nkc = 0; ncc = cc + 1; }
        if (ncc < NCO) {
          const uint16_t* p = wbf + (size_t)(ncc * 128 + swc) * 256 + nkc * 32 + swh * 16;
          wr0 = *(const uint4*)(p);
          wr1 = *(const uint4*)(p + 8);
        }
      }
      __syncthreads();
      vec8s bf[4];
      #pragma unroll
      for (int pf = 0; pf < 4; ++pf)
        bf[pf] = *(const vec8s*)&sX[wp * 64 + pf * 16 + l15][kc * 32 + koct * 8];
      #pragma unroll
      for (int cf = 0; cf < 4; ++cf) {
        vec8s af = *(const vec8s*)&sW[wc * 64 + cf * 16 + l15][koct * 8];
        #pragma unroll
        for (int pf = 0; pf < 4; ++pf)
          acc[cf][pf] = __builtin_amdgcn_mfma_f32_16x16x32_bf16(af, bf[pf], acc[cf][pf], 0, 0, 0);
      }
    }

    // ---- epilogue ----
    #pragma unroll
    for (int cf = 0; cf < 4; ++cf) {
      const int cbase = cc * 128 + wc * 64 + cf * 16 + koct * 4;
      if constexpr (OUT_MODE == 2) {
        float scv[4], shv[4];
        #pragma unroll
        for (int r = 0; r < 4; ++r) {
          int c = cbase + r;
          float g = bnp[c], be = bnp[256 + c], mu = bnp[512 + c], va = bnp[768 + c];
          scv[r] = g * rsqrtf(va + 1e-5f);
          shv[r] = be - mu * scv[r];
        }
        #pragma unroll
        for (int pf = 0; pf < 4; ++pf) {
          int px = tile * 128 + wp * 64 + pf * 16 + l15;
          #pragma unroll
          for (int r = 0; r < 4; ++r)
            outf[(size_t)(b * 256 + cbase + r) * HW + px] =
                fmaf(acc[cf][pf][r], scv[r], shv[r]);
        }
      } else {   // OUT_MODE 4: fused pre+qkv
        if (cc < 2) {
          float scv[4], shv[4];
          #pragma unroll
          for (int r = 0; r < 4; ++r) {
            int c = cbase + r;
            float g = bnp[c], be = bnp[256 + c], mu = bnp[512 + c], va = bnp[768 + c];
            scv[r] = g * rsqrtf(va + 1e-5f);
            shv[r] = be - mu * scv[r];
          }
          #pragma unroll
          for (int pf = 0; pf < 4; ++pf) {
            int e = wp * 64 + pf * 16 + l15;
            int win = tile * 2 + (e >> 6);
            int p = e & 63;
            int gpx = ((win >> 4) * 8 + (p >> 3)) * 128 + (win & 15) * 8 + (p & 7);
            __align__(8) uint16_t pk[4];
            #pragma unroll
            for (int r = 0; r < 4; ++r)
              pk[r] = f2bf(fmaf(acc[cf][pf][r], scv[r], shv[r]));
            *(uint2*)(outbPre + ((size_t)b * HW + gpx) * 256 + cbase) = *(uint2*)pk;
          }
        } else {
          const int c0 = cbase - 256;   // qkv channel base
          #pragma unroll
          for (int pf = 0; pf < 4; ++pf) {
            int win = tile * 2 + wp;
            int p = pf * 16 + l15;
            uint16_t* dstp = outbQkv + ((size_t)(b * 256 + win) * 768 + c0) * 64 + p;
            #pragma unroll
            for (int r = 0; r < 4; ++r)
              dstp[(size_t)r * 64] = f2bf(acc[cf][pf][r]);
          }
        }
      }
    }
  }
}

// ---------------------------------------------------------------------------
// Dilated 3x3 conv + BN via bf16 MFMA implicit GEMM (unchanged from r3).
// ---------------------------------------------------------------------------
template<int DIL, int CG>
__global__ __launch_bounds__(256) void k_dilconv_mfma(
    const uint16_t* __restrict__ preT, const float* __restrict__ wt,
    const float* __restrict__ bnp, float* __restrict__ out,
    int cb, int cb_al)
{
  constexpr int R = 8 + 2 * DIL;
  constexpr int C = 64 + 2 * DIL;
  constexpr int NPOS = R * C;
  constexpr int NIT = (NPOS + 255) / 256;
  __shared__ __align__(16) uint16_t sX[NPOS * 16];
  __shared__ __align__(16) uint16_t sW[10 * 50 * 16];

  const int t = threadIdx.x;
  const int rt    = blockIdx.x >> 1;
  const int ctile = blockIdx.x & 1;
  const int ct2   = blockIdx.y;
  const int b     = blockIdx.z;
  const int y0 = rt * 8, x0 = ctile * 64;
  const int l = t & 63, w = t >> 6;
  const int l15 = l & 15, oct = (l >> 4) & 1, half = l >> 5;
  const int rbase = w * 2;

  f32x4 acc[3][8];
  #pragma unroll
  for (int cf = 0; cf < 3; ++cf)
    #pragma unroll
    for (int q = 0; q < 8; ++q) acc[cf][q] = (f32x4){0.f,0.f,0.f,0.f};

  for (int kc = 0; kc < 6; ++kc) {
    #pragma unroll
    for (int i = 0; i < 3; ++i) {
      int pair = t + i * 256;
      int co = pair >> 4, ci = pair & 15;
      int cog = ct2 * 48 + co;
      int c = cb_al + kc * 16 + ci;
      bool ok = (cog < CG) && (c >= cb) && (c < cb + CG);
      size_t widx = ok ? ((size_t)cog * (size_t)CG + (size_t)(c - cb)) * 9u
                       : (size_t)0;
      const float* wp = wt + widx;
      uint16_t* dst = &sW[co * 16 + ci];
      #pragma unroll
      for (int tap = 0; tap < 9; ++tap)
        dst[tap * 800] = ok ? f2bf(wp[tap]) : (uint16_t)0;
      dst[9 * 800] = 0;
    }
    #pragma unroll
    for (int i = 0; i < NIT; ++i) {
      int p = t + i * 256;
      if (p < NPOS) {
        int row = p / C, col = p % C;
        int gy = y0 + row - DIL, gx = x0 + col - DIL;
        uint4 va = {0,0,0,0}, vb = {0,0,0,0};
        if ((unsigned)gy < 128u && (unsigned)gx < 128u) {
          const uint4* src = (const uint4*)(preT +
              (((size_t)b * HW + gy * 128 + gx) * 256 + cb_al + kc * 16));
          va = src[0]; vb = src[1];
        }
        uint4* dst = (uint4*)&sX[p * 16];
        dst[0] = va; dst[1] = vb;
      }
    }
    __syncthreads();

    #pragma unroll
    for (int s = 0; s < 5; ++s) {
      const int tap0 = 2 * s, tap1 = 2 * s + 1;
      const int dy0 = tap0 / 3, dx0 = tap0 % 3;
      const int dy1 = (tap1 <= 8) ? tap1 / 3 : 2;
      const int dx1 = (tap1 <= 8) ? tap1 % 3 : 2;
      const int dy = half ? dy1 : dy0;
      const int dx = half ? dx1 : dx0;
      const int atap = tap0 + half;
      vec8s a0 = *(const vec8s*)&sW[(atap * 50 + 0  + l15) * 16 + oct * 8];
      vec8s a1 = *(const vec8s*)&sW[(atap * 50 + 16 + l15) * 16 + oct * 8];
      vec8s a2 = *(const vec8s*)&sW[(atap * 50 + 32 + l15) * 16 + oct * 8];
      #pragma unroll
      for (int rs = 0; rs < 2; ++rs) {
        const int rowin = rbase + rs + dy * DIL;
        #pragma unroll
        for (int c4 = 0; c4 < 4; ++c4) {
          const int colin = c4 * 16 + l15 + dx * DIL;
          vec8s bf = *(const vec8s*)&sX[(rowin * C + colin) * 16 + oct * 8];
          acc[0][rs*4+c4] = __builtin_amdgcn_mfma_f32_16x16x32_bf16(a0, bf, acc[0][rs*4+c4], 0, 0, 0);
          acc[1][rs*4+c4] = __builtin_amdgcn_mfma_f32_16x16x32_bf16(a1, bf, acc[1][rs*4+c4], 0, 0, 0);
          acc[2][rs*4+c4] = __builtin_amdgcn_mfma_f32_16x16x32_bf16(a2, bf, acc[2][rs*4+c4], 0, 0, 0);
        }
      }
    }
    __syncthreads();
  }

  const int row4 = (l >> 4);
  #pragma unroll
  for (int cf = 0; cf < 3; ++cf) {
    #pragma unroll
    for (int r = 0; r < 4; ++r) {
      int c_loc = ct2 * 48 + cf * 16 + row4 * 4 + r;
      if (c_loc < CG) {
        int cg = cb + c_loc;
        float g = bnp[c_loc], be = bnp[CG + c_loc];
        float mu = bnp[2 * CG + c_loc], va = bnp[3 * CG + c_loc];
        float scv = g * rsqrtf(va + 1e-5f);
        float shv = be - mu * scv;
        #pragma unroll
        for (int rs = 0; rs < 2; ++rs) {
          int y = y0 + rbase + rs;
          #pragma unroll
          for (int c4 = 0; c4 < 4; ++c4) {
            int x = x0 + c4 * 16 + l15;
            out[(size_t)(b * 256 + cg) * HW + y * 128 + x] =
                fmaf(acc[cf][rs*4+c4][r], scv, shv);
          }
        }
      }
    }
  }
}

// ---------------------------------------------------------------------------
// Windowed attention v3 (unchanged from r13): overlay + SW pipeline.
// ---------------------------------------------------------------------------
__global__ __launch_bounds__(256) void k_attn(
    const uint16_t* __restrict__ qkvW, const float* __restrict__ rpb,
    uint16_t* __restrict__ outp)
{
  __shared__ __align__(16) uint16_t sAll[4][5632];
  const int t = threadIdx.x;
  const int l = t & 63, w = t >> 6;
  const int l15 = l & 15, koct = l >> 4;
  const int b = blockIdx.y;
  const int win = blockIdx.x;
  const int wy = win >> 4, wx = win & 15;
  const int wbase = (wy * 8) * 128 + wx * 8;
  const uint16_t* base = qkvW + (size_t)(b * 256 + win) * 49152;
  uint16_t* swKT = &sAll[w][0];
  uint16_t* swQT = &sAll[w][2560];
  uint16_t* swPT = &sAll[w][0];
  float*    swO  = (float*)&sAll[w][0];
  float*    swB  = (float*)&sAll[w][5120];

  const uint16_t* qg = base + (size_t)(w * 16) * 64;
  const uint16_t* kg = qg + 256 * 64;
  const uint16_t* vg = qg + 512 * 64;
  uint32_t kp[8], qp[8];
  float breg[4];
  #pragma unroll
  for (int m = 0; m < 8; ++m) {
    uint32_t k0 = kg[(2 * m) * 64 + l], k1 = kg[(2 * m + 1) * 64 + l];
    uint32_t q0 = qg[(2 * m) * 64 + l], q1 = qg[(2 * m + 1) * 64 + l];
    kp[m] = k0 | (k1 << 16);
    qp[m] = q0 | (q1 << 16);
  }
  #pragma unroll
  for (int m = 0; m < 4; ++m) {
    int e = l + m * 64;
    breg[m] = (e < 225) ? rpb[e * 16 + w] : 0.f;
  }

  for (int it = 0; it < 4; ++it) {
    const int n = w + it * 4;
    #pragma unroll
    for (int m = 0; m < 4; ++m) {
      int e = l + m * 64;
      if (e < 225) swB[e] = breg[m];
    }
    {
      uint4 z = {0, 0, 0, 0};
      *(uint4*)(swKT + l * 40)      = *(uint4*)&kp[0];
      *(uint4*)(swKT + l * 40 + 8)  = *(uint4*)&kp[4];
      *(uint4*)(swKT + l * 40 + 16) = z;
      *(uint4*)(swKT + l * 40 + 24) = z;
      *(uint4*)(swQT + l * 40)      = *(uint4*)&qp[0];
      *(uint4*)(swQT + l * 40 + 8)  = *(uint4*)&qp[4];
      *(uint4*)(swQT + l * 40 + 16) = z;
      *(uint4*)(swQT + l * 40 + 24) = z;
    }
    vec8s vA0 = *(const vec8s*)(vg + l15 * 64 + koct * 8);
    vec8s vA1 = *(const vec8s*)(vg + l15 * 64 + 32 + koct * 8);
    if (it < 3) {
      const uint16_t* qg2 = qg + 4096;
      const uint16_t* kg2 = kg + 4096;
      #pragma unroll
      for (int m = 0; m < 8; ++m) {
        uint32_t k0 = kg2[(2 * m) * 64 + l], k1 = kg2[(2 * m + 1) * 64 + l];
        uint32_t q0 = qg2[(2 * m) * 64 + l], q1 = qg2[(2 * m + 1) * 64 + l];
        kp[m] = k0 | (k1 << 16);
        qp[m] = q0 | (q1 << 16);
      }
      #pragma unroll
      for (int m = 0; m < 4; ++m) {
        int e = l + m * 64;
        breg[m] = (e < 225) ? rpb[e * 16 + n + 4] : 0.f;
      }
    }
    asm volatile("s_waitcnt lgkmcnt(0)" ::: "memory");
    __builtin_amdgcn_sched_barrier(0);

    vec8s aK[4], bQ[4];
    #pragma unroll
    for (int tt = 0; tt < 4; ++tt) {
      aK[tt] = *(const vec8s*)(swKT + (tt * 16 + l15) * 40 + koct * 8);
      bQ[tt] = *(const vec8s*)(swQT + (tt * 16 + l15) * 40 + koct * 8);
    }
    f32x4 accS[4][4];
    #pragma unroll
    for (int ti = 0; ti < 4; ++ti)
      #pragma unroll
      for (int tj = 0; tj < 4; ++tj)
        accS[ti][tj] = __builtin_amdgcn_mfma_f32_16x16x32_bf16(
            aK[tj], bQ[ti], (f32x4){0.f, 0.f, 0.f, 0.f}, 0, 0, 0);

    float p[4][16], sinv[4];
    #pragma unroll
    for (int ti = 0; ti < 4; ++ti) {
      const int i = ti * 16 + l15;
      const int irow = i >> 3, icol = i & 7;
      #pragma unroll
      for (int tj = 0; tj < 4; ++tj) {
        #pragma unroll
        for (int r = 0; r < 4; ++r) {
          int j = tj * 16 + koct * 4 + r;
          int rel = (irow - (j >> 3) + 7) * 15 + (icol - (j & 7) + 7);
          p[ti][tj * 4 + r] = fmaf(accS[ti][tj][r], 0.25f, swB[rel]);
        }
      }
      float mx = p[ti][0];
      #pragma unroll
      for (int u = 1; u < 16; ++u) mx = fmaxf(mx, p[ti][u]);
      mx = fmaxf(mx, __shfl_xor(mx, 16));
      mx = fmaxf(mx, __shfl_xor(mx, 32));
      float s = 0.f;
      #pragma unroll
      for (int u = 0; u < 16; ++u) { p[ti][u] = __expf(p[ti][u] - mx); s += p[ti][u]; }
      s += __shfl_xor(s, 16);
      s += __shfl_xor(s, 32);
      sinv[ti] = 1.f / s;
    }

    #pragma unroll
    for (int ti = 0; ti < 4; ++ti) {
      uint16_t* rowp = swPT + (ti * 16 + l15) * 68 + koct * 4;
      #pragma unroll
      for (int tj = 0; tj < 4; ++tj) {
        uint32_t u0 = (uint32_t)f2bf(p[ti][tj * 4 + 0]) | ((uint32_t)f2bf(p[ti][tj * 4 + 1]) << 16);
        uint32_t u1 = (uint32_t)f2bf(p[ti][tj * 4 + 2]) | ((uint32_t)f2bf(p[ti][tj * 4 + 3]) << 16);
        *(uint32_t*)(rowp + tj * 16)     = u0;
        *(uint32_t*)(rowp + tj * 16 + 2) = u1;
      }
    }
    asm volatile("s_waitcnt lgkmcnt(0)" ::: "memory");
    __builtin_amdgcn_sched_barrier(0);

    f32x4 accO[4];
    #pragma unroll
    for (int ii = 0; ii < 4; ++ii) accO[ii] = (f32x4){0.f, 0.f, 0.f, 0.f};
    #pragma unroll
    for (int ks = 0; ks < 2; ++ks) {
      vec8s aV = ks ? vA1 : vA0;
      #pragma unroll
      for (int ii = 0; ii < 4; ++ii) {
        vec8s bP;
        const uint16_t* src = swPT + (ii * 16 + l15) * 68 + ks * 32 + koct * 8;
        *(uint2*)&bP       = *(const uint2*)(src);
        *((uint2*)&bP + 1) = *(const uint2*)(src + 4);
        accO[ii] = __builtin_amdgcn_mfma_f32_16x16x32_bf16(aV, bP, accO[ii], 0, 0, 0);
      }
    }
    asm volatile("s_waitcnt lgkmcnt(0)" ::: "memory");
    __builtin_amdgcn_sched_barrier(0);

    #pragma unroll
    for (int ii = 0; ii < 4; ++ii) {
      #pragma unroll
      for (int r = 0; r < 4; ++r) {
        int dd = koct * 4 + r;
        swO[dd * 76 + ii * 16 + l15] = accO[ii][r] * sinv[ii];
      }
    }
    asm volatile("s_waitcnt lgkmcnt(0)" ::: "memory");
    __builtin_amdgcn_sched_barrier(0);
    #pragma unroll
    for (int e2 = 0; e2 < 2; ++e2) {
      int e = l + e2 * 64;
      int dd = e >> 3, row = e & 7;
      const float* orow = swO + dd * 76 + row * 8;
      float4 a = *(const float4*)(orow);
      float4 c = *(const float4*)(orow + 4);
      uint4 pk;
      pk.x = (uint32_t)f2bf(a.x) | ((uint32_t)f2bf(a.y) << 16);
      pk.y = (uint32_t)f2bf(a.z) | ((uint32_t)f2bf(a.w) << 16);
      pk.z = (uint32_t)f2bf(c.x) | ((uint32_t)f2bf(c.y) << 16);
      pk.w = (uint32_t)f2bf(c.z) | ((uint32_t)f2bf(c.w) << 16);
      *(uint4*)(outp + (size_t)(b * 256 + n * 16 + dd) * HW + wbase + row * 128) = pk;
    }
    asm volatile("s_waitcnt lgkmcnt(0)" ::: "memory");
    __builtin_amdgcn_sched_barrier(0);
    qg += 4096; kg += 4096; vg += 4096;
  }
}

// ---------------------------------------------------------------------------
// combined = avgpool_v(attn) + avgpool_h(attn) + local (unchanged from r9).
// ---------------------------------------------------------------------------
__global__ __launch_bounds__(256) void k_pool(
    const uint16_t* __restrict__ attnb, float* __restrict__ loc)
{
  __shared__ __align__(16) float sP[71][136];
  const int t = threadIdx.x;
  const int plane = blockIdx.x >> 1;
  const int h0 = (blockIdx.x & 1) * 64;
  const size_t pbase = (size_t)plane * HW;
  #pragma unroll
  for (int k = 0; k < 5; ++k) {
    int idx = t + k * 256;
    if (idx < 71 * 16) {
      int lr = idx >> 4, m = idx & 15;
      int g = h0 - 3 + lr;
      float f[8] = {0.f,0.f,0.f,0.f,0.f,0.f,0.f,0.f};
      if (g >= 0 && g <= 127) {
        uint4 v4 = *(const uint4*)(attnb + pbase + (size_t)g * 128 + m * 8);
        unpack2(v4.x, f[0], f[1]); unpack2(v4.y, f[2], f[3]);
        unpack2(v4.z, f[4], f[5]); unpack2(v4.w, f[6], f[7]);
      }
      float* dst = &sP[lr][4 + m * 8];
      *(float4*)dst       = (float4){f[0], f[1], f[2], f[3]};
      *(float4*)(dst + 4) = (float4){f[4], f[5], f[6], f[7]};
    }
  }
  #pragma unroll
  for (int k = 0; k < 3; ++k) {
    int idx = t + k * 256;
    if (idx < 71 * 8) {
      int lr = idx >> 3, e = idx & 7;
      int c = (e < 4) ? e : (128 + e);
      sP[lr][c] = 0.f;
    }
  }
  __syncthreads();

  const int q  = t & 31;
  const int r0 = (t >> 5) * 8;
  const int w0 = q * 4;
  float4 av = {0.f, 0.f, 0.f, 0.f};
  #pragma unroll
  for (int o = 0; o < 8; ++o) {
    float4 v = *(const float4*)&sP[r0 + o][4 + w0];
    av.x += v.x; av.y += v.y; av.z += v.z; av.w += v.w;
  }
  #pragma unroll
  for (int rr = 0; rr < 8; ++rr) {
    const int lh = r0 + rr;
    const int h = h0 + lh;
    float4 a = av;
    if (h >= 124) {
      float4 cfix = *(const float4*)&sP[126 - 64 + 3][4 + w0];
      a.x += cfix.x; a.y += cfix.y; a.z += cfix.z; a.w += cfix.w;
    }
    float4 hv0 = *(const float4*)&sP[lh + 3][w0];
    float4 hv1 = *(const float4*)&sP[lh + 3][w0 + 4];
    float4 hv2 = *(const float4*)&sP[lh + 3][w0 + 8];
    float s0 = hv0.y + hv0.z + hv0.w + hv1.x + hv1.y + hv1.z + hv1.w + hv2.x;
    float s1 = s0 - hv0.y + hv2.y;
    float s2 = s1 - hv0.z + hv2.z;
    float s3 = s2 - hv0.w + hv2.w;
    if (q == 31) {
      float cfix = sP[lh + 3][130];
      s0 += cfix; s1 += cfix; s2 += cfix; s3 += cfix;
    }
    const size_t gi = pbase + (size_t)h * 128 + w0;
    float4 lv = *(const float4*)(loc + gi);
    float4 o4;
    o4.x = fmaf(a.x + s0, 0.125f, lv.x);
    o4.y = fmaf(a.y + s1, 0.125f, lv.y);
    o4.z = fmaf(a.z + s2, 0.125f, lv.z);
    o4.w = fmaf(a.w + s3, 0.125f, lv.w);
    *(float4*)(loc + gi) = o4;
    if (rr < 7) {
      float4 vm = *(const float4*)&sP[lh][4 + w0];
      float4 vp = *(const float4*)&sP[lh + 8][4 + w0];
      av.x += vp.x - vm.x; av.y += vp.y - vm.y;
      av.z += vp.z - vm.z; av.w += vp.w - vm.w;
    }
  }
}

// ---------------------------------------------------------------------------
// Depthwise 8x8 conv (unchanged from r10).
// ---------------------------------------------------------------------------
__global__ __launch_bounds__(256) void k_dw(
    const float* __restrict__ comb, const float* __restrict__ wdw,
    float* __restrict__ out)
{
  __shared__ __align__(16) float sZ[71][136];
  __shared__ float sWd[64];
  const int t = threadIdx.x;
  const int plane = blockIdx.x >> 1;
  const int cch = plane & 255;
  const int h0 = (blockIdx.x & 1) * 64;
  const size_t pbase = (size_t)plane * HW;
  if (t < 64) sWd[t] = wdw[cch * 64 + t];
  #pragma unroll
  for (int k = 0; k < 5; ++k) {
    int idx = t + k * 256;
    if (idx < 71 * 16) {
      int lr = idx >> 4, m = idx & 15;
      int g = h0 - 3 + lr;
      float4 a = {0.f,0.f,0.f,0.f}, c = {0.f,0.f,0.f,0.f};
      if (g >= 0 && g <= 128) {
        int gr = (g == 128) ? 126 : g;
        const float* src = comb + pbase + (size_t)gr * 128 + m * 8;
        a = *(const float4*)(src);
        c = *(const float4*)(src + 4);
      }
      float* dst = &sZ[lr][4 + m * 8];
      *(float4*)dst       = a;
      *(float4*)(dst + 4) = c;
    }
  }
  if (t < 71) {
    int lr = t;
    int g = h0 - 3 + lr;
    float rv = 0.f;
    if (g >= 0 && g <= 128) {
      int gr = (g == 128) ? 126 : g;
      rv = comb[pbase + (size_t)gr * 128 + 126];
    }
    *(float4*)&sZ[lr][0] = (float4){0.f, 0.f, 0.f, 0.f};
    sZ[lr][132] = rv;
    sZ[lr][133] = 0.f; sZ[lr][134] = 0.f; sZ[lr][135] = 0.f;
  }
  __syncthreads();

  float wt[8][8];
  #pragma unroll
  for (int i = 0; i < 8; ++i) {
    *(float4*)&wt[i][0] = *(const float4*)&sWd[i * 8];
    *(float4*)&wt[i][4] = *(const float4*)&sWd[i * 8 + 4];
  }

  const int q  = t & 31;
  const int rg = t >> 5;
  const int w0 = q * 4;
  f32x4 acc[8];
  #pragma unroll
  for (int rr = 0; rr < 8; ++rr) acc[rr] = (f32x4){0.f,0.f,0.f,0.f};

  #pragma unroll
  for (int v = 0; v < 15; ++v) {
    const int lr = rg * 8 + v;
    float win[12];
    *(float4*)&win[0] = *(const float4*)&sZ[lr][w0];
    *(float4*)&win[4] = *(const float4*)&sZ[lr][w0 + 4];
    *(float4*)&win[8] = *(const float4*)&sZ[lr][w0 + 8];
    #pragma unroll
    for (int rr = 0; rr < 8; ++rr) {
      const int i = v - rr;
      if (i >= 0 && i < 8) {
        #pragma unroll
        for (int c = 0; c < 4; ++c) {
          float s = acc[rr][c];
          #pragma unroll
          for (int j = 0; j < 8; ++j)
            s = fmaf(wt[i][j], win[c + j + 1], s);
          acc[rr][c] = s;
        }
      }
    }
  }
  #pragma unroll
  for (int rr = 0; rr < 8; ++rr) {
    int h = h0 + rg * 8 + rr;
    float* dst = out + pbase + (size_t)h * 128 + w0;
    *(float4*)dst = (float4){acc[rr][0], acc[rr][1], acc[rr][2], acc[rr][3]};
  }
}

} // namespace

extern "C" void kernel_launch(void* const* d_in, const int* in_sizes, int n_in,
                              void* d_out, int out_size, void* d_ws, size_t ws_size,
                              hipStream_t stream)
{
  const float* x      = (const float*)d_in[0];
  const float* w_pre  = (const float*)d_in[1];
  const float* bn_pre = (const float*)d_in[2];
  const float* w_l1   = (const float*)d_in[3];
  const float* bn_l1  = (const float*)d_in[4];
  const float* w_l2   = (const float*)d_in[5];
  const float* bn_l2  = (const float*)d_in[6];
  const float* w_l3   = (const float*)d_in[7];
  const float* bn_l3  = (const float*)d_in[8];
  const float* w_qkv  = (const float*)d_in[9];
  const float* rpb    = (const float*)d_in[10];
  const float* w_dw   = (const float*)d_in[11];
  const float* w_pw   = (const float*)d_in[12];
  const float* bn_pj  = (const float*)d_in[13];
  float* out = (float*)d_out;

  char* base = (char*)d_ws;
  uint16_t* preT  = (uint16_t*)(base + (size_t)67108864);     // 64 MiB NHWC bf16 pre; later attn out; later wpw_bf
  float*    bufB  = (float*)(base + (size_t)134217728);       // 128 MiB fp32 local/combined
  uint16_t* bufQ  = (uint16_t*)(base + (size_t)268435456);    // 192 MiB bf16 qkv windows; later dw out
  uint16_t* attnO = preT;
  float*    bufDw = (float*)bufQ;
  // bf16 weights: wcomb = [wpre(256 rows) ; wqkv(768 rows)] contiguous in d_out
  uint16_t* wcomb_bf = (uint16_t*)out;
  uint16_t* wpw_bf   = preT;

  dim3 blk(256);
  // W pre-conversion: wpre rows then wqkv rows, contiguous
  k_w2bf<<<dim3(32),  blk, 0, stream>>>(w_pre, wcomb_bf, 65536);
  k_w2bf<<<dim3(96),  blk, 0, stream>>>(w_qkv, wcomb_bf + 65536, 196608);
  // 1. FUSED pre+qkv from NCHW fp32 x (win-major X tile):
  //    pre -> preT (NHWC bf16+BN), qkv -> bufQ (window layout bf16)
  k_gemm_v4<4, 8, true><<<dim3(1024), blk, 0, stream>>>(
      x, wcomb_bf, bn_pre, preT, bufQ, nullptr);
  // 2. dilated 3x3 convs + bn (MFMA) -> bufB fp32 NCHW
  k_dilconv_mfma<1, 86><<<dim3(32, 2, 8), blk, 0, stream>>>(preT, w_l1, bn_l1, bufB, 0, 0);
  k_dilconv_mfma<2, 86><<<dim3(32, 2, 8), blk, 0, stream>>>(preT, w_l2, bn_l2, bufB, 86, 80);
  k_dilconv_mfma<3, 84><<<dim3(32, 2, 8), blk, 0, stream>>>(preT, w_l3, bn_l3, bufB, 172, 160);
  // 3. windowed attention -> attnO bf16 NCHW (overwrites preT; safe)
  k_attn<<<dim3(256, 8), blk, 0, stream>>>(bufQ, rpb, attnO);
  // 4. pools + residual combine (in-place on bufB)
  k_pool<<<dim3(4096), blk, 0, stream>>>(attnO, bufB);
  // 4b. wpw -> bf16 into preT region (attnO dead after pool)
  k_w2bf<<<dim3(32), blk, 0, stream>>>(w_pw, wpw_bf, 65536);
  // 5. depthwise 8x8 -> bufDw fp32 NCHW (overwrites bufQ; safe)
  k_dw<<<dim3(4096), blk, 0, stream>>>(bufB, w_dw, bufDw);
  // 6. pw 1x1 conv + bn from NCHW fp32 bufDw (direct stage) -> out
  k_gemm_v4<2, 2, false><<<dim3(1024), blk, 0, stream>>>(
      bufDw, wpw_bf, bn_pj, nullptr, nullptr, out);

  (void)in_sizes; (void)n_in; (void)out_size; (void)ws_size;
}